// Round 5
// baseline (890.399 us; speedup 1.0000x reference)
//
#include <hip/hip_runtime.h>
#include <stdint.h>

#define D_MODEL 1024
#define EXP_D   4096
#define NE      8
#define NTOK    8192
#define BMT     128
#define MAX_TILES 136
#define NS_MAX  17408   // MAX_TILES*128

typedef __attribute__((ext_vector_type(8))) short short8;
typedef __attribute__((ext_vector_type(4))) float f32x4;
typedef __attribute__((ext_vector_type(4))) unsigned short us4;

// ---- workspace layout (bytes) ----
#define WS_COUNTS    0          // int[8]
#define WS_CURSORS   32         // int[8]
#define WS_PADOFF    64         // int[16]
#define WS_META      128        // int[32], meta[0]=ntiles
#define WS_TILE_E    256        // int[256]
#define WS_PP        4096       // float[2048*8]
#define WS_TOP_E     69632      // int[16384]
#define WS_TOP_W     135168     // float[16384]
#define WS_SLOT_W    270336     // float[17408]
#define WS_TOK_SLOT  339968     // int[16384]
#define WS_XG        405504     // bf16 [17408][1024]  (Yb aliases this)
#define WS_HB        36057088   // bf16 [17408][4096]
#define WS_WB        178663424  // bf16 [8][4096][1024] -> ends 245,772,288

__device__ __forceinline__ unsigned short f2bf(float f){
  __bf16 h = (__bf16)f;
  return __builtin_bit_cast(unsigned short, h);
}
__device__ __forceinline__ float bf2f(unsigned short u){
  unsigned int v = ((unsigned int)u) << 16;
  return __builtin_bit_cast(float, v);
}
__device__ __forceinline__ void gl_lds16(const void* g, void* l){
  __builtin_amdgcn_global_load_lds((const __attribute__((address_space(1))) unsigned int*)g,
                                   (__attribute__((address_space(3))) unsigned int*)l,
                                   16, 0, 0);
}

template<int N> __device__ __forceinline__ void vmw(){
  if constexpr (N==0)       asm volatile("s_waitcnt vmcnt(0)"  ::: "memory");
  else if constexpr (N==5)  asm volatile("s_waitcnt vmcnt(5)"  ::: "memory");
  else if constexpr (N==6)  asm volatile("s_waitcnt vmcnt(6)"  ::: "memory");
  else if constexpr (N==10) asm volatile("s_waitcnt vmcnt(10)" ::: "memory");
  else if constexpr (N==12) asm volatile("s_waitcnt vmcnt(12)" ::: "memory");
}

// ---------------- init: zero 64-int header ----------------
__global__ void init_kernel(int* __restrict__ hdr){
  if (threadIdx.x < 64) hdr[threadIdx.x] = 0;
}

// ---------------- weight fp32 -> bf16 convert ----------------
__global__ __launch_bounds__(256) void cvt_kernel(const float* __restrict__ W,
                                                  unsigned short* __restrict__ Wb){
  const int n4 = NE*EXP_D*D_MODEL/4;
  for (int i = blockIdx.x*256 + threadIdx.x; i < n4; i += gridDim.x*256){
    const float4 v = *(const float4*)&W[(size_t)i*4];
    us4 o; o[0]=f2bf(v.x); o[1]=f2bf(v.y); o[2]=f2bf(v.z); o[3]=f2bf(v.w);
    *(us4*)&Wb[(size_t)i*4] = o;
  }
}

// ---------------- router: one wave per token ----------------
__global__ __launch_bounds__(256) void router_kernel(
    const float* __restrict__ x, const float* __restrict__ Wr,
    const float* __restrict__ br,
    int* __restrict__ counts, int* __restrict__ top_e, float* __restrict__ top_w,
    float* __restrict__ pp)
{
  __shared__ float WrS[NE*D_MODEL];
  __shared__ float wprob[4][NE];
  const int tid = threadIdx.x;
#pragma unroll
  for (int i=0;i<8;++i){
    int j = (tid + i*256)*4;
    *(float4*)&WrS[j] = *(const float4*)&Wr[j];
  }
  __syncthreads();
  const int w = tid>>6, lane = tid&63;
  const int t = blockIdx.x*4 + w;
  const float* xt = x + (size_t)t*D_MODEL;
  float accv[8] = {0,0,0,0,0,0,0,0};
#pragma unroll
  for (int i=0;i<4;++i){
    const int k = i*256 + lane*4;
    const float4 xv = *(const float4*)&xt[k];
#pragma unroll
    for (int e=0;e<8;++e){
      const float4 wv = *(const float4*)&WrS[e*D_MODEL + k];
      accv[e] += xv.x*wv.x + xv.y*wv.y + xv.z*wv.z + xv.w*wv.w;
    }
  }
#pragma unroll
  for (int m=32;m>0;m>>=1){
#pragma unroll
    for (int e=0;e<8;++e) accv[e] += __shfl_xor(accv[e], m, 64);
  }
  if (lane==0){
    float lg[8];
#pragma unroll
    for (int e=0;e<8;++e) lg[e] = accv[e] + br[e];
    float mx = lg[0];
#pragma unroll
    for (int e=1;e<8;++e) mx = fmaxf(mx, lg[e]);
    float p[8]; float s=0.f;
#pragma unroll
    for (int e=0;e<8;++e){ p[e] = __expf(lg[e]-mx); s += p[e]; }
    const float inv = 1.f/s;
#pragma unroll
    for (int e=0;e<8;++e){ p[e] *= inv; wprob[w][e] = p[e]; }
    int i1=0; float p1v=p[0];
#pragma unroll
    for (int e=1;e<8;++e) if (p[e] > p1v){ p1v=p[e]; i1=e; }
    int i2=-1; float p2v=-1.f;
#pragma unroll
    for (int e=0;e<8;++e) if (e!=i1 && p[e] > p2v){ p2v=p[e]; i2=e; }
    const float rn = 1.f/(p1v+p2v);
    top_e[2*t]   = i1; top_w[2*t]   = p1v*rn;
    top_e[2*t+1] = i2; top_w[2*t+1] = p2v*rn;
    atomicAdd(&counts[i1],1);
    atomicAdd(&counts[i2],1);
  }
  __syncthreads();
  if (tid<8){
    pp[blockIdx.x*8+tid] = wprob[0][tid]+wprob[1][tid]+wprob[2][tid]+wprob[3][tid];
  }
}

// ---------------- prefix: tile table + aux loss ----------------
__global__ void prefix_kernel(int* __restrict__ wsI, const float* __restrict__ pp,
                              float* __restrict__ aux_out){
  const int tid = threadIdx.x;
  __shared__ float dev2[8];
  if (tid==0){
    int* counts = wsI + 0;
    int* padoff = wsI + 16;
    int* meta   = wsI + 32;
    int* tileE  = wsI + 64;
    int nt = 0;
    for (int e=0;e<NE;++e){
      padoff[e] = nt*BMT;
      int tiles = (counts[e] + BMT - 1) >> 7;
      for (int i=0;i<tiles;++i) tileE[nt++] = e;
    }
    meta[0] = nt;
  }
  if (tid<8){
    float s=0.f;
    for (int b=0;b<NTOK/4;++b) s += pp[b*8+tid];
    float d = s*(1.f/(float)NTOK) - 0.125f;
    dev2[tid] = d*d;
  }
  __syncthreads();
  if (tid==0){
    float a=0.f;
#pragma unroll
    for (int e=0;e<8;++e) a += dev2[e];
    aux_out[0] = a;
  }
}

// ---------------- scatter: LDS-aggregated atomics ----------------
__global__ __launch_bounds__(1024) void scatter_kernel(
    const int* __restrict__ top_e, const float* __restrict__ top_w,
    int* __restrict__ cursors, const int* __restrict__ padoff,
    float* __restrict__ slot_w, int* __restrict__ tok_slot)
{
  __shared__ int cnt[NE];
  __shared__ int base[NE];
  const int tid = threadIdx.x;
  if (tid < NE) cnt[tid] = 0;
  __syncthreads();
  const int t = blockIdx.x*1024 + tid;
  const int e0 = top_e[2*t], e1 = top_e[2*t+1];
  const float w0v = top_w[2*t], w1v = top_w[2*t+1];
  const int p0 = atomicAdd(&cnt[e0], 1);
  const int p1 = atomicAdd(&cnt[e1], 1);
  __syncthreads();
  if (tid < NE) base[tid] = atomicAdd(&cursors[tid], cnt[tid]);
  __syncthreads();
  const int s0 = padoff[e0] + base[e0] + p0;
  const int s1 = padoff[e1] + base[e1] + p1;
  slot_w[s0] = w0v; slot_w[s1] = w1v;
  tok_slot[2*t] = s0; tok_slot[2*t+1] = s1;
}

// ---------------- gather: wave per token ----------------
__global__ __launch_bounds__(256) void gather_kernel(
    const float* __restrict__ x, const int* __restrict__ tok_slot,
    unsigned short* __restrict__ Xg)
{
  const int w = threadIdx.x>>6, lane = threadIdx.x&63;
  const int t = blockIdx.x*4 + w;
  const int s0 = tok_slot[2*t], s1 = tok_slot[2*t+1];
  us4 o[4];
#pragma unroll
  for (int i=0;i<4;++i){
    const float4 v = *(const float4*)&x[(size_t)t*D_MODEL + i*256 + lane*4];
    o[i][0]=f2bf(v.x); o[i][1]=f2bf(v.y); o[i][2]=f2bf(v.z); o[i][3]=f2bf(v.w);
  }
#pragma unroll
  for (int i=0;i<4;++i) *(us4*)&Xg[(size_t)s0*D_MODEL + i*256 + lane*4] = o[i];
#pragma unroll
  for (int i=0;i<4;++i) *(us4*)&Xg[(size_t)s1*D_MODEL + i*256 + lane*4] = o[i];
}

// ============ grouped GEMM: BM=128 x BN, per-wave 128x64, BK=32 ============
// Software-pipelined: ds_reads for phase k+1 issue before phase k's MFMA;
// counted vmcnt; single barrier per K-tile; swizzled LDS (chunk ^= (row>>2)&3).
template<int KT, int NT, int BN, int WAVES, int NBUF, bool G2>
__global__ __launch_bounds__(WAVES*64, 2) void moe_gemm_p(
    const unsigned short* __restrict__ A,
    const unsigned short* __restrict__ Wb,
    const float* __restrict__ bias,
    unsigned short* __restrict__ Cout,
    const int* __restrict__ tileE,
    const int* __restrict__ meta,
    const float* __restrict__ slotw)
{
  constexpr int NX = NT/BN;
  constexpr int TOTAL = NX*MAX_TILES;
  constexpr int Q = TOTAL/8, R = TOTAL%8;
  constexpr int NTILES = KT/32;
  constexpr int SA = 8/WAVES;            // A gl_lds per wave per K-tile
  constexpr int SB = BN/(16*WAVES);      // B gl_lds per wave per K-tile
  constexpr int SPK = SA+SB;
  constexpr int LEAD = NBUF-1;
  constexpr int VMS = (NBUF-2)*SPK;      // steady vmcnt
  constexpr int VM3 = (NBUF==4)? SPK : VMS;
  constexpr bool STG3 = (NBUF==3);
  constexpr int BUFSZ = (128+BN)*64;

  const int lid = blockIdx.x;
  const int xcc = lid & 7, jj = lid >> 3;
  const int tsw = xcc*Q + (xcc < R ? xcc : R) + jj;
  const int mtile = tsw / NX, ntile = tsw - mtile*NX;
  if (mtile >= meta[0]) return;

  extern __shared__ char smem[];
  const int tid  = threadIdx.x;
  const int w    = tid >> 6, lane = tid & 63;
  const int e    = tileE[mtile];
  const int m0   = mtile * BMT;
  const int n0   = ntile * BN;

  // fragment read addressing (per-lane, loop-invariant)
  const int r15  = lane & 15;
  const int swz  = (((lane>>4) ^ ((lane>>2)&3)) << 4);
  const int abyte = r15*64 + swz;                 // + mf*1024
  const int bbyte = w*4096 + r15*64 + swz;        // + nf*1024 (+8192 B base)

  // staging source (pre-swizzled global chunk)
  const int c4 = (lane&3) ^ ((lane>>4)&3);
  const unsigned short* srcA = A  + (size_t)(m0 + w*16 + (lane>>2))*KT + c4*8;
  const unsigned short* srcB = Wb + (size_t)e*NT*KT
                             + (size_t)(n0 + w*16 + (lane>>2))*KT + c4*8;

  char* bufs[4];
  bufs[0]=smem; bufs[1]=smem+BUFSZ; bufs[2]=smem+2*BUFSZ;
  bufs[3]=(NBUF==4)? smem+3*BUFSZ : smem;

#define STAGE(BS, TT) do{                                                         \
    const size_t kbe = (size_t)(TT)*32;                                           \
    _Pragma("unroll")                                                             \
    for (int ii=0; ii<SA; ++ii)                                                   \
      gl_lds16(srcA + kbe + (size_t)(ii*WAVES*16)*KT, (BS) + (w + ii*WAVES)*1024);\
    _Pragma("unroll")                                                             \
    for (int jq=0; jq<SB; ++jq)                                                   \
      gl_lds16(srcB + kbe + (size_t)(jq*WAVES*16)*KT,                             \
               (BS) + 8192 + (w + jq*WAVES)*1024);                                \
  }while(0)

  f32x4 acc[8][4];
#pragma unroll
  for (int i=0;i<8;++i)
#pragma unroll
    for (int j=0;j<4;++j) acc[i][j] = (f32x4){0.f,0.f,0.f,0.f};

  short8 A0[4], A1[4], Ba[4], Bb[4];

#define MF_ROW(ai, AX, BC)                                                        \
    acc[ai][0]=__builtin_amdgcn_mfma_f32_16x16x32_bf16(BC[0],AX,acc[ai][0],0,0,0);\
    acc[ai][1]=__builtin_amdgcn_mfma_f32_16x16x32_bf16(BC[1],AX,acc[ai][1],0,0,0);\
    acc[ai][2]=__builtin_amdgcn_mfma_f32_16x16x32_bf16(BC[2],AX,acc[ai][2],0,0,0);\
    acc[ai][3]=__builtin_amdgcn_mfma_f32_16x16x32_bf16(BC[3],AX,acc[ai][3],0,0,0);

#define KTILE(BT, BT1, BS, BC, BNX, VMN, DOSTG, TSTG, LAST) do{                   \
    /* ph0: issue A-hi reads for this tile, then MFMA on lo-half */               \
    A1[0] = *(const short8*)((BT) + 4*1024 + abyte);                              \
    A1[1] = *(const short8*)((BT) + 5*1024 + abyte);                              \
    A1[2] = *(const short8*)((BT) + 6*1024 + abyte);                              \
    A1[3] = *(const short8*)((BT) + 7*1024 + abyte);                              \
    __builtin_amdgcn_sched_barrier(0);                                            \
    __builtin_amdgcn_s_setprio(1);                                                \
    MF_ROW(0, A0[0], BC) MF_ROW(1, A0[1], BC)                                     \
    MF_ROW(2, A0[2], BC) MF_ROW(3, A0[3], BC)                                     \
    __builtin_amdgcn_s_setprio(0);                                                \
    __builtin_amdgcn_sched_barrier(0);                                            \
    /* ph1 */                                                                     \
    if (!(LAST)){                                                                 \
      if (DOSTG){ STAGE(BS, TSTG); }                                              \
      vmw<VMN>();                                                                 \
      asm volatile("s_waitcnt lgkmcnt(0)" ::: "memory");                          \
      __builtin_amdgcn_s_barrier();                                               \
      A0[0] = *(const short8*)((BT1) + 0*1024 + abyte);                           \
      A0[1] = *(const short8*)((BT1) + 1*1024 + abyte);                           \
      A0[2] = *(const short8*)((BT1) + 2*1024 + abyte);                           \
      A0[3] = *(const short8*)((BT1) + 3*1024 + abyte);                           \
      BNX[0] = *(const short8*)((BT1) + 8192 + 0*1024 + bbyte);                   \
      BNX[1] = *(const short8*)((BT1) + 8192 + 1*1024 + bbyte);                   \
      BNX[2] = *(const short8*)((BT1) + 8192 + 2*1024 + bbyte);                   \
      BNX[3] = *(const short8*)((BT1) + 8192 + 3*1024 + bbyte);                   \
    }                                                                             \
    __builtin_amdgcn_sched_barrier(0);                                            \
    __builtin_amdgcn_s_setprio(1);                                                \
    MF_ROW(4, A1[0], BC) MF_ROW(5, A1[1], BC)                                     \
    MF_ROW(6, A1[2], BC) MF_ROW(7, A1[3], BC)                                     \
    __builtin_amdgcn_s_setprio(0);                                                \
    __builtin_amdgcn_sched_barrier(0);                                            \
  }while(0)

  // prologue: stage buffers 0..LEAD-1, wait buf0, preload t=0 fragments
#pragma unroll
  for (int s=0; s<LEAD; ++s) STAGE(bufs[s], s);
  vmw<VMS>();
  __builtin_amdgcn_s_barrier();
  A0[0] = *(const short8*)(bufs[0] + 0*1024 + abyte);
  A0[1] = *(const short8*)(bufs[0] + 1*1024 + abyte);
  A0[2] = *(const short8*)(bufs[0] + 2*1024 + abyte);
  A0[3] = *(const short8*)(bufs[0] + 3*1024 + abyte);
  Ba[0] = *(const short8*)(bufs[0] + 8192 + 0*1024 + bbyte);
  Ba[1] = *(const short8*)(bufs[0] + 8192 + 1*1024 + bbyte);
  Ba[2] = *(const short8*)(bufs[0] + 8192 + 2*1024 + bbyte);
  Ba[3] = *(const short8*)(bufs[0] + 8192 + 3*1024 + bbyte);

  int bi = 0;
#pragma unroll 1
  for (int t = 0; t < NTILES-4; t += 2){
    const int b1 = (bi+1==NBUF)?0:bi+1;
    const int bs = (bi==0)?NBUF-1:bi-1;
    KTILE(bufs[bi], bufs[b1], bufs[bs], Ba, Bb, VMS, true, t+LEAD, false);
    const int b2 = (b1+1==NBUF)?0:b1+1;
    KTILE(bufs[b1], bufs[b2], bufs[bi], Bb, Ba, VMS, true, t+1+LEAD, false);
    bi = b2;
  }
  { // t = NTILES-4 (B set: Ba)
    const int b1 = (bi+1==NBUF)?0:bi+1;
    const int bs = (bi==0)?NBUF-1:bi-1;
    KTILE(bufs[bi], bufs[b1], bufs[bs], Ba, Bb, VMS, true, NTILES-4+LEAD, false);
    bi = b1;
  }
  { // t = NTILES-3 (Bb)
    const int b1 = (bi+1==NBUF)?0:bi+1;
    const int bs = (bi==0)?NBUF-1:bi-1;
    KTILE(bufs[bi], bufs[b1], bufs[bs], Bb, Ba, VM3, STG3, NTILES-3+LEAD, false);
    bi = b1;
  }
  { // t = NTILES-2 (Ba)
    const int b1 = (bi+1==NBUF)?0:bi+1;
    KTILE(bufs[bi], bufs[b1], bufs[bi], Ba, Bb, 0, false, 0, false);
    bi = b1;
  }
  { // t = NTILES-1 (Bb), last
    KTILE(bufs[bi], bufs[bi], bufs[bi], Bb, Ba, 0, false, 0, true);
  }
#undef KTILE
#undef MF_ROW
#undef STAGE

  // epilogue: lane holds 4 consecutive n per fragment
  const int ng4 = (lane >> 4)*4;
#pragma unroll
  for (int mi=0; mi<8; ++mi){
    const int m = m0 + mi*16 + r15;
    float wg = 0.f;
    if (G2) wg = slotw[m];
#pragma unroll
    for (int nf=0; nf<4; ++nf){
      const int nb = n0 + w*64 + nf*16 + ng4;
      const float4 bv = *(const float4*)&bias[(size_t)e*NT + nb];
      float q0 = acc[mi][nf][0] + bv.x;
      float q1 = acc[mi][nf][1] + bv.y;
      float q2 = acc[mi][nf][2] + bv.z;
      float q3 = acc[mi][nf][3] + bv.w;
      if (!G2){
        q0=fmaxf(q0,0.f); q1=fmaxf(q1,0.f); q2=fmaxf(q2,0.f); q3=fmaxf(q3,0.f);
      } else {
        q0*=wg; q1*=wg; q2*=wg; q3*=wg;
      }
      us4 o; o[0]=f2bf(q0); o[1]=f2bf(q1); o[2]=f2bf(q2); o[3]=f2bf(q3);
      *(us4*)&Cout[(size_t)m*NT + nb] = o;
    }
  }
}

// ---------------- combine: out[t] = Y[slot0] + Y[slot1] ----------------
__global__ __launch_bounds__(256) void combine_kernel(
    const unsigned short* __restrict__ Yb, const int* __restrict__ tok_slot,
    float* __restrict__ out)
{
  const int t = blockIdx.x;
  const int tid = threadIdx.x;
  const int s0 = tok_slot[2*t], s1 = tok_slot[2*t+1];
  const us4 a = *(const us4*)&Yb[(size_t)s0*D_MODEL + tid*4];
  const us4 b = *(const us4*)&Yb[(size_t)s1*D_MODEL + tid*4];
  float4 o;
  o.x = bf2f(a[0]) + bf2f(b[0]);
  o.y = bf2f(a[1]) + bf2f(b[1]);
  o.z = bf2f(a[2]) + bf2f(b[2]);
  o.w = bf2f(a[3]) + bf2f(b[3]);
  *(float4*)&out[(size_t)t*D_MODEL + tid*4] = o;
}

extern "C" void kernel_launch(void* const* d_in, const int* in_sizes, int n_in,
                              void* d_out, int out_size, void* d_ws, size_t ws_size,
                              hipStream_t stream)
{
  const float* x  = (const float*)d_in[0];
  const float* Wr = (const float*)d_in[1];
  const float* br = (const float*)d_in[2];
  const float* W1 = (const float*)d_in[3];
  const float* b1 = (const float*)d_in[4];
  const float* W2 = (const float*)d_in[5];
  const float* b2 = (const float*)d_in[6];
  float* out = (float*)d_out;
  char* ws = (char*)d_ws;

  int*   counts  = (int*)(ws + WS_COUNTS);
  int*   cursors = (int*)(ws + WS_CURSORS);
  int*   padoff  = (int*)(ws + WS_PADOFF);
  int*   meta    = (int*)(ws + WS_META);
  int*   tileE   = (int*)(ws + WS_TILE_E);
  float* pp      = (float*)(ws + WS_PP);
  int*   top_e   = (int*)(ws + WS_TOP_E);
  float* top_w   = (float*)(ws + WS_TOP_W);
  float* slot_w  = (float*)(ws + WS_SLOT_W);
  int*   tok_slot= (int*)(ws + WS_TOK_SLOT);
  unsigned short* Xg = (unsigned short*)(ws + WS_XG);
  unsigned short* Hb = (unsigned short*)(ws + WS_HB);
  unsigned short* Wb = (unsigned short*)(ws + WS_WB);
  unsigned short* Yb = Xg;   // Xg dead after GEMM1

  // GEMM1: K=1024, N=4096, BN=512, 8 waves, 4 LDS buffers (160 KB)
  // GEMM2: K=4096, N=1024, BN=256, 4 waves, 3 LDS buffers (72 KB, 2 blk/CU)
  hipFuncSetAttribute((const void*)moe_gemm_p<D_MODEL, EXP_D, 512, 8, 4, false>,
                      hipFuncAttributeMaxDynamicSharedMemorySize, 163840);
  hipFuncSetAttribute((const void*)moe_gemm_p<EXP_D, D_MODEL, 256, 4, 3, true>,
                      hipFuncAttributeMaxDynamicSharedMemorySize, 73728);

  init_kernel<<<dim3(1), dim3(64), 0, stream>>>((int*)ws);
  router_kernel<<<dim3(NTOK/4), dim3(256), 0, stream>>>(x, Wr, br, counts, top_e, top_w, pp);
  prefix_kernel<<<dim3(1), dim3(256), 0, stream>>>((int*)ws, pp, out + (size_t)NTOK*D_MODEL);
  scatter_kernel<<<dim3(NTOK/1024), dim3(1024), 0, stream>>>(top_e, top_w, cursors, padoff,
                                                             slot_w, tok_slot);
  gather_kernel<<<dim3(NTOK/4), dim3(256), 0, stream>>>(x, tok_slot, Xg);
  cvt_kernel<<<dim3(2048), dim3(256), 0, stream>>>(W1, Wb);
  moe_gemm_p<D_MODEL, EXP_D, 512, 8, 4, false>
      <<<dim3((EXP_D/512)*MAX_TILES), dim3(512), 163840, stream>>>(
      Xg, Wb, b1, Hb, tileE, meta, slot_w);
  cvt_kernel<<<dim3(2048), dim3(256), 0, stream>>>(W2, Wb);
  moe_gemm_p<EXP_D, D_MODEL, 256, 4, 3, true>
      <<<dim3((D_MODEL/256)*MAX_TILES), dim3(256), 73728, stream>>>(
      Hb, Wb, b2, Yb, tileE, meta, slot_w);
  combine_kernel<<<dim3(NTOK), dim3(256), 0, stream>>>(Yb, tok_slot, out);
}

// Round 6
// 725.080 us; speedup vs baseline: 1.2280x; 1.2280x over previous
//
#include <hip/hip_runtime.h>
#include <stdint.h>

#define D_MODEL 1024
#define EXP_D   4096
#define NE      8
#define NTOK    8192
#define BMT     128
#define MAX_TILES 136
#define NS_MAX  17408   // MAX_TILES*128

typedef __attribute__((ext_vector_type(8))) short short8;
typedef __attribute__((ext_vector_type(4))) float f32x4;
typedef __attribute__((ext_vector_type(4))) unsigned short us4;

// ---- workspace layout (bytes) ----
#define WS_COUNTS    0          // int[8]
#define WS_CURSORS   32         // int[8]
#define WS_PADOFF    64         // int[16]
#define WS_META      128        // int[32], meta[0]=ntiles
#define WS_TILE_E    256        // int[256]
#define WS_PP        4096       // float[2048*8]
#define WS_TOP_E     69632      // int[16384]
#define WS_TOP_W     135168     // float[16384]
#define WS_SLOT_W    270336     // float[17408]
#define WS_TOK_SLOT  339968     // int[16384]
#define WS_XG        405504     // bf16 [17408][1024]  (Yb aliases this)
#define WS_HB        36057088   // bf16 [17408][4096]
#define WS_WB        178663424  // bf16 [8][4096][1024] -> ends 245,772,288

__device__ __forceinline__ unsigned short f2bf(float f){
  __bf16 h = (__bf16)f;
  return __builtin_bit_cast(unsigned short, h);
}
__device__ __forceinline__ float bf2f(unsigned short u){
  unsigned int v = ((unsigned int)u) << 16;
  return __builtin_bit_cast(float, v);
}
__device__ __forceinline__ void gl_lds16(const void* g, void* l){
  __builtin_amdgcn_global_load_lds((const __attribute__((address_space(1))) unsigned int*)g,
                                   (__attribute__((address_space(3))) unsigned int*)l,
                                   16, 0, 0);
}

template<int N> __device__ __forceinline__ void vmw(){
  if constexpr (N==0)      asm volatile("s_waitcnt vmcnt(0)" ::: "memory");
  else if constexpr (N==6) asm volatile("s_waitcnt vmcnt(6)" ::: "memory");
}

// ---------------- init: zero 64-int header ----------------
__global__ void init_kernel(int* __restrict__ hdr){
  if (threadIdx.x < 64) hdr[threadIdx.x] = 0;
}

// ---------------- weight fp32 -> bf16 convert ----------------
__global__ __launch_bounds__(256) void cvt_kernel(const float* __restrict__ W,
                                                  unsigned short* __restrict__ Wb){
  const int n4 = NE*EXP_D*D_MODEL/4;
  for (int i = blockIdx.x*256 + threadIdx.x; i < n4; i += gridDim.x*256){
    const float4 v = *(const float4*)&W[(size_t)i*4];
    us4 o; o[0]=f2bf(v.x); o[1]=f2bf(v.y); o[2]=f2bf(v.z); o[3]=f2bf(v.w);
    *(us4*)&Wb[(size_t)i*4] = o;
  }
}

// ---------------- router: one wave per token ----------------
__global__ __launch_bounds__(256) void router_kernel(
    const float* __restrict__ x, const float* __restrict__ Wr,
    const float* __restrict__ br,
    int* __restrict__ counts, int* __restrict__ top_e, float* __restrict__ top_w,
    float* __restrict__ pp)
{
  __shared__ float WrS[NE*D_MODEL];
  __shared__ float wprob[4][NE];
  const int tid = threadIdx.x;
#pragma unroll
  for (int i=0;i<8;++i){
    int j = (tid + i*256)*4;
    *(float4*)&WrS[j] = *(const float4*)&Wr[j];
  }
  __syncthreads();
  const int w = tid>>6, lane = tid&63;
  const int t = blockIdx.x*4 + w;
  const float* xt = x + (size_t)t*D_MODEL;
  float accv[8] = {0,0,0,0,0,0,0,0};
#pragma unroll
  for (int i=0;i<4;++i){
    const int k = i*256 + lane*4;
    const float4 xv = *(const float4*)&xt[k];
#pragma unroll
    for (int e=0;e<8;++e){
      const float4 wv = *(const float4*)&WrS[e*D_MODEL + k];
      accv[e] += xv.x*wv.x + xv.y*wv.y + xv.z*wv.z + xv.w*wv.w;
    }
  }
#pragma unroll
  for (int m=32;m>0;m>>=1){
#pragma unroll
    for (int e=0;e<8;++e) accv[e] += __shfl_xor(accv[e], m, 64);
  }
  if (lane==0){
    float lg[8];
#pragma unroll
    for (int e=0;e<8;++e) lg[e] = accv[e] + br[e];
    float mx = lg[0];
#pragma unroll
    for (int e=1;e<8;++e) mx = fmaxf(mx, lg[e]);
    float p[8]; float s=0.f;
#pragma unroll
    for (int e=0;e<8;++e){ p[e] = __expf(lg[e]-mx); s += p[e]; }
    const float inv = 1.f/s;
#pragma unroll
    for (int e=0;e<8;++e){ p[e] *= inv; wprob[w][e] = p[e]; }
    int i1=0; float p1v=p[0];
#pragma unroll
    for (int e=1;e<8;++e) if (p[e] > p1v){ p1v=p[e]; i1=e; }
    int i2=-1; float p2v=-1.f;
#pragma unroll
    for (int e=0;e<8;++e) if (e!=i1 && p[e] > p2v){ p2v=p[e]; i2=e; }
    const float rn = 1.f/(p1v+p2v);
    top_e[2*t]   = i1; top_w[2*t]   = p1v*rn;
    top_e[2*t+1] = i2; top_w[2*t+1] = p2v*rn;
    atomicAdd(&counts[i1],1);
    atomicAdd(&counts[i2],1);
  }
  __syncthreads();
  if (tid<8){
    pp[blockIdx.x*8+tid] = wprob[0][tid]+wprob[1][tid]+wprob[2][tid]+wprob[3][tid];
  }
}

// ---------------- prefix: tile table + aux loss ----------------
__global__ void prefix_kernel(int* __restrict__ wsI, const float* __restrict__ pp,
                              float* __restrict__ aux_out){
  const int tid = threadIdx.x;
  __shared__ float dev2[8];
  if (tid==0){
    int* counts = wsI + 0;
    int* padoff = wsI + 16;
    int* meta   = wsI + 32;
    int* tileE  = wsI + 64;
    int nt = 0;
    for (int e=0;e<NE;++e){
      padoff[e] = nt*BMT;
      int tiles = (counts[e] + BMT - 1) >> 7;
      for (int i=0;i<tiles;++i) tileE[nt++] = e;
    }
    meta[0] = nt;
  }
  if (tid<8){
    float s=0.f;
    for (int b=0;b<NTOK/4;++b) s += pp[b*8+tid];
    float d = s*(1.f/(float)NTOK) - 0.125f;
    dev2[tid] = d*d;
  }
  __syncthreads();
  if (tid==0){
    float a=0.f;
#pragma unroll
    for (int e=0;e<8;++e) a += dev2[e];
    aux_out[0] = a;
  }
}

// ---------------- scatter: LDS-aggregated atomics ----------------
__global__ __launch_bounds__(1024) void scatter_kernel(
    const int* __restrict__ top_e, const float* __restrict__ top_w,
    int* __restrict__ cursors, const int* __restrict__ padoff,
    float* __restrict__ slot_w, int* __restrict__ tok_slot)
{
  __shared__ int cnt[NE];
  __shared__ int base[NE];
  const int tid = threadIdx.x;
  if (tid < NE) cnt[tid] = 0;
  __syncthreads();
  const int t = blockIdx.x*1024 + tid;
  const int e0 = top_e[2*t], e1 = top_e[2*t+1];
  const float w0v = top_w[2*t], w1v = top_w[2*t+1];
  const int p0 = atomicAdd(&cnt[e0], 1);
  const int p1 = atomicAdd(&cnt[e1], 1);
  __syncthreads();
  if (tid < NE) base[tid] = atomicAdd(&cursors[tid], cnt[tid]);
  __syncthreads();
  const int s0 = padoff[e0] + base[e0] + p0;
  const int s1 = padoff[e1] + base[e1] + p1;
  slot_w[s0] = w0v; slot_w[s1] = w1v;
  tok_slot[2*t] = s0; tok_slot[2*t+1] = s1;
}

// ---------------- gather: wave per token ----------------
__global__ __launch_bounds__(256) void gather_kernel(
    const float* __restrict__ x, const int* __restrict__ tok_slot,
    unsigned short* __restrict__ Xg)
{
  const int w = threadIdx.x>>6, lane = threadIdx.x&63;
  const int t = blockIdx.x*4 + w;
  const int s0 = tok_slot[2*t], s1 = tok_slot[2*t+1];
  us4 o[4];
#pragma unroll
  for (int i=0;i<4;++i){
    const float4 v = *(const float4*)&x[(size_t)t*D_MODEL + i*256 + lane*4];
    o[i][0]=f2bf(v.x); o[i][1]=f2bf(v.y); o[i][2]=f2bf(v.z); o[i][3]=f2bf(v.w);
  }
#pragma unroll
  for (int i=0;i<4;++i) *(us4*)&Xg[(size_t)s0*D_MODEL + i*256 + lane*4] = o[i];
#pragma unroll
  for (int i=0;i<4;++i) *(us4*)&Xg[(size_t)s1*D_MODEL + i*256 + lane*4] = o[i];
}

// ============ grouped GEMM: 128x256 tile, BK=64, 8 waves, 3-buf K-tile pipeline ============
// C[m][n] = sum_k A[m][k] * W[e][n][k]  (+bias; G1: relu; G2: *slot_w[m])
// Buffer (48KB): A rows0-127 @0, B rows0-255 @16384.  Swizzle: chunk ^= row&7 (both sides).
template<int KT, int NT, bool G2>
__global__ __launch_bounds__(512,1) void moe_gemm3(
    const unsigned short* __restrict__ A,
    const unsigned short* __restrict__ Wb,
    const float* __restrict__ bias,
    unsigned short* __restrict__ Cout,
    const int* __restrict__ tileE,
    const int* __restrict__ meta,
    const float* __restrict__ slotw)
{
  constexpr int NX = NT/256;
  constexpr int TOTAL = NX*MAX_TILES;
  constexpr int Q = TOTAL/8, R = TOTAL%8;
  constexpr int NTILES = KT/64;
  static_assert((NTILES-4)%3 == 0, "tail peel needs (NTILES-4)%3==0");

  const int lid = blockIdx.x;
  const int xcc = lid & 7, jj = lid >> 3;
  const int tsw = xcc*Q + (xcc < R ? xcc : R) + jj;
  const int mtile = tsw / NX, ntile = tsw - mtile*NX;
  if (mtile >= meta[0]) return;

  extern __shared__ char smem[];
  char* const BUF0 = smem;
  char* const BUF1 = smem + 49152;
  char* const BUF2 = smem + 98304;

  const int tid = threadIdx.x;
  const int w = tid>>6, lane = tid&63;
  const int wr = w>>2, wn = w&3;
  const int r15 = lane&15, kg = lane>>4;
  const int e  = tileE[mtile];
  const int m0 = mtile*BMT;
  const int n0 = ntile*256;

  // staging source (pre-swizzled global chunk: phys chunk t&7 holds logical (t&7)^(row&7))
  const int trow = tid>>3;
  const int tch  = ((tid&7) ^ (trow&7))*8;
  const unsigned short* sA = A  + (size_t)(m0 + trow)*KT + tch;
  const unsigned short* sB = Wb + (size_t)e*NT*KT + (size_t)(n0 + trow)*KT + tch;

#define STG_ABL(BS, KTT) do{ \
    gl_lds16(sA + (size_t)(KTT)*64,                  (BS) + tid*16); \
    gl_lds16(sA + (size_t)(KTT)*64 + (size_t)64*KT,  (BS) + 8192  + tid*16); \
    gl_lds16(sB + (size_t)(KTT)*64,                  (BS) + 16384 + tid*16); \
    gl_lds16(sB + (size_t)(KTT)*64 + (size_t)64*KT,  (BS) + 24576 + tid*16); \
  }while(0)
#define STG_BH(BS, KTT) do{ \
    gl_lds16(sB + (size_t)(KTT)*64 + (size_t)128*KT, (BS) + 32768 + tid*16); \
    gl_lds16(sB + (size_t)(KTT)*64 + (size_t)192*KT, (BS) + 40960 + tid*16); \
  }while(0)

  // fragment read offsets (ks=0); ks=1 = offset ^ 64 (chunk ^= 4)
  const int key4 = (kg ^ (r15&7))<<4;
  const int a0 = (wr*64 + 0*16 + r15)*128 + key4;
  const int a1 = (wr*64 + 1*16 + r15)*128 + key4;
  const int a2 = (wr*64 + 2*16 + r15)*128 + key4;
  const int a3 = (wr*64 + 3*16 + r15)*128 + key4;
  const int b0 = 16384 + (wn*64 + 0*16 + r15)*128 + key4;
  const int b1 = 16384 + (wn*64 + 1*16 + r15)*128 + key4;
  const int b2 = 16384 + (wn*64 + 2*16 + r15)*128 + key4;
  const int b3 = 16384 + (wn*64 + 3*16 + r15)*128 + key4;

  f32x4 acc[4][4];
#pragma unroll
  for (int i=0;i<4;++i)
#pragma unroll
    for (int j=0;j<4;++j) acc[i][j] = (f32x4){0.f,0.f,0.f,0.f};

#define PHASE(BC, KS, STG_STMT, VM_STMT) do{ \
    const int kx_ = (KS)*64; \
    short8 af0 = *(const short8*)((BC) + (a0 ^ kx_)); \
    short8 af1 = *(const short8*)((BC) + (a1 ^ kx_)); \
    short8 af2 = *(const short8*)((BC) + (a2 ^ kx_)); \
    short8 af3 = *(const short8*)((BC) + (a3 ^ kx_)); \
    short8 bv0 = *(const short8*)((BC) + (b0 ^ kx_)); \
    short8 bv1 = *(const short8*)((BC) + (b1 ^ kx_)); \
    short8 bv2 = *(const short8*)((BC) + (b2 ^ kx_)); \
    short8 bv3 = *(const short8*)((BC) + (b3 ^ kx_)); \
    STG_STMT; \
    VM_STMT; \
    __builtin_amdgcn_sched_barrier(0); \
    __builtin_amdgcn_s_barrier(); \
    __builtin_amdgcn_sched_barrier(0); \
    __builtin_amdgcn_s_setprio(1); \
    acc[0][0]=__builtin_amdgcn_mfma_f32_16x16x32_bf16(bv0,af0,acc[0][0],0,0,0); \
    acc[0][1]=__builtin_amdgcn_mfma_f32_16x16x32_bf16(bv1,af0,acc[0][1],0,0,0); \
    acc[0][2]=__builtin_amdgcn_mfma_f32_16x16x32_bf16(bv2,af0,acc[0][2],0,0,0); \
    acc[0][3]=__builtin_amdgcn_mfma_f32_16x16x32_bf16(bv3,af0,acc[0][3],0,0,0); \
    acc[1][0]=__builtin_amdgcn_mfma_f32_16x16x32_bf16(bv0,af1,acc[1][0],0,0,0); \
    acc[1][1]=__builtin_amdgcn_mfma_f32_16x16x32_bf16(bv1,af1,acc[1][1],0,0,0); \
    acc[1][2]=__builtin_amdgcn_mfma_f32_16x16x32_bf16(bv2,af1,acc[1][2],0,0,0); \
    acc[1][3]=__builtin_amdgcn_mfma_f32_16x16x32_bf16(bv3,af1,acc[1][3],0,0,0); \
    acc[2][0]=__builtin_amdgcn_mfma_f32_16x16x32_bf16(bv0,af2,acc[2][0],0,0,0); \
    acc[2][1]=__builtin_amdgcn_mfma_f32_16x16x32_bf16(bv1,af2,acc[2][1],0,0,0); \
    acc[2][2]=__builtin_amdgcn_mfma_f32_16x16x32_bf16(bv2,af2,acc[2][2],0,0,0); \
    acc[2][3]=__builtin_amdgcn_mfma_f32_16x16x32_bf16(bv3,af2,acc[2][3],0,0,0); \
    acc[3][0]=__builtin_amdgcn_mfma_f32_16x16x32_bf16(bv0,af3,acc[3][0],0,0,0); \
    acc[3][1]=__builtin_amdgcn_mfma_f32_16x16x32_bf16(bv1,af3,acc[3][1],0,0,0); \
    acc[3][2]=__builtin_amdgcn_mfma_f32_16x16x32_bf16(bv2,af3,acc[3][2],0,0,0); \
    acc[3][3]=__builtin_amdgcn_mfma_f32_16x16x32_bf16(bv3,af3,acc[3][3],0,0,0); \
    __builtin_amdgcn_s_setprio(0); \
    __builtin_amdgcn_sched_barrier(0); \
    __builtin_amdgcn_s_barrier(); \
  }while(0)

// steady tile: compute buf BC, stage K-tile KTT into BS; vmcnt(6) waits tile T+1
#define TILE_STEADY(BC, BS, KTT) do{ \
    PHASE(BC, 0, STG_ABL(BS, KTT), (void)0); \
    PHASE(BC, 1, STG_BH(BS, KTT),  vmw<6>()); \
  }while(0)

  // prologue: stage tiles 0 (buf0) and 1 (buf1); wait tile 0
  STG_ABL(BUF0, 0); STG_BH(BUF0, 0);
  STG_ABL(BUF1, 1); STG_BH(BUF1, 1);
  vmw<6>();
  __builtin_amdgcn_s_barrier();

#pragma unroll 1
  for (int i = 0; i < (NTILES-4)/3; ++i){
    const int kt = i*3;
    TILE_STEADY(BUF0, BUF2, kt+2);
    TILE_STEADY(BUF1, BUF0, kt+3);
    TILE_STEADY(BUF2, BUF1, kt+4);
  }
  TILE_STEADY(BUF0, BUF2, NTILES-2);   // tile NT-4
  TILE_STEADY(BUF1, BUF0, NTILES-1);   // tile NT-3
  { // tile NT-2 (buf2): no stage; drain remaining (tile NT-1's) loads
    PHASE(BUF2, 0, (void)0, (void)0);
    PHASE(BUF2, 1, (void)0, vmw<0>());
  }
  { // tile NT-1 (buf0)
    PHASE(BUF0, 0, (void)0, (void)0);
    PHASE(BUF0, 1, (void)0, (void)0);
  }
#undef PHASE
#undef TILE_STEADY
#undef STG_ABL
#undef STG_BH

  // epilogue: lane r15 <-> m, (lane>>4)*4 + reg <-> n  (verified layout, round 4)
  const int ng4 = kg*4;
#pragma unroll
  for (int mf=0; mf<4; ++mf){
    const int m = m0 + wr*64 + mf*16 + r15;
    float wg = 0.f;
    if (G2) wg = slotw[m];
#pragma unroll
    for (int nf=0; nf<4; ++nf){
      const int nb = n0 + wn*64 + nf*16 + ng4;
      const float4 bv = *(const float4*)&bias[(size_t)e*NT + nb];
      float q0 = acc[mf][nf][0] + bv.x;
      float q1 = acc[mf][nf][1] + bv.y;
      float q2 = acc[mf][nf][2] + bv.z;
      float q3 = acc[mf][nf][3] + bv.w;
      if (!G2){
        q0=fmaxf(q0,0.f); q1=fmaxf(q1,0.f); q2=fmaxf(q2,0.f); q3=fmaxf(q3,0.f);
      } else {
        q0*=wg; q1*=wg; q2*=wg; q3*=wg;
      }
      us4 o; o[0]=f2bf(q0); o[1]=f2bf(q1); o[2]=f2bf(q2); o[3]=f2bf(q3);
      *(us4*)&Cout[(size_t)m*NT + nb] = o;
    }
  }
}

// ---------------- combine: out[t] = Y[slot0] + Y[slot1] ----------------
__global__ __launch_bounds__(256) void combine_kernel(
    const unsigned short* __restrict__ Yb, const int* __restrict__ tok_slot,
    float* __restrict__ out)
{
  const int t = blockIdx.x;
  const int tid = threadIdx.x;
  const int s0 = tok_slot[2*t], s1 = tok_slot[2*t+1];
  const us4 a = *(const us4*)&Yb[(size_t)s0*D_MODEL + tid*4];
  const us4 b = *(const us4*)&Yb[(size_t)s1*D_MODEL + tid*4];
  float4 o;
  o.x = bf2f(a[0]) + bf2f(b[0]);
  o.y = bf2f(a[1]) + bf2f(b[1]);
  o.z = bf2f(a[2]) + bf2f(b[2]);
  o.w = bf2f(a[3]) + bf2f(b[3]);
  *(float4*)&out[(size_t)t*D_MODEL + tid*4] = o;
}

extern "C" void kernel_launch(void* const* d_in, const int* in_sizes, int n_in,
                              void* d_out, int out_size, void* d_ws, size_t ws_size,
                              hipStream_t stream)
{
  const float* x  = (const float*)d_in[0];
  const float* Wr = (const float*)d_in[1];
  const float* br = (const float*)d_in[2];
  const float* W1 = (const float*)d_in[3];
  const float* b1 = (const float*)d_in[4];
  const float* W2 = (const float*)d_in[5];
  const float* b2 = (const float*)d_in[6];
  float* out = (float*)d_out;
  char* ws = (char*)d_ws;

  int*   counts  = (int*)(ws + WS_COUNTS);
  int*   cursors = (int*)(ws + WS_CURSORS);
  int*   padoff  = (int*)(ws + WS_PADOFF);
  int*   meta    = (int*)(ws + WS_META);
  int*   tileE   = (int*)(ws + WS_TILE_E);
  float* pp      = (float*)(ws + WS_PP);
  int*   top_e   = (int*)(ws + WS_TOP_E);
  float* top_w   = (float*)(ws + WS_TOP_W);
  float* slot_w  = (float*)(ws + WS_SLOT_W);
  int*   tok_slot= (int*)(ws + WS_TOK_SLOT);
  unsigned short* Xg = (unsigned short*)(ws + WS_XG);
  unsigned short* Hb = (unsigned short*)(ws + WS_HB);
  unsigned short* Wb = (unsigned short*)(ws + WS_WB);
  unsigned short* Yb = Xg;   // Xg dead after GEMM1

  hipFuncSetAttribute((const void*)moe_gemm3<D_MODEL, EXP_D, false>,
                      hipFuncAttributeMaxDynamicSharedMemorySize, 147456);
  hipFuncSetAttribute((const void*)moe_gemm3<EXP_D, D_MODEL, true>,
                      hipFuncAttributeMaxDynamicSharedMemorySize, 147456);

  init_kernel<<<dim3(1), dim3(64), 0, stream>>>((int*)ws);
  router_kernel<<<dim3(NTOK/4), dim3(256), 0, stream>>>(x, Wr, br, counts, top_e, top_w, pp);
  prefix_kernel<<<dim3(1), dim3(256), 0, stream>>>((int*)ws, pp, out + (size_t)NTOK*D_MODEL);
  scatter_kernel<<<dim3(NTOK/1024), dim3(1024), 0, stream>>>(top_e, top_w, cursors, padoff,
                                                             slot_w, tok_slot);
  gather_kernel<<<dim3(NTOK/4), dim3(256), 0, stream>>>(x, tok_slot, Xg);
  cvt_kernel<<<dim3(2048), dim3(256), 0, stream>>>(W1, Wb);
  moe_gemm3<D_MODEL, EXP_D, false>
      <<<dim3((EXP_D/256)*MAX_TILES), dim3(512), 147456, stream>>>(
      Xg, Wb, b1, Hb, tileE, meta, slot_w);
  cvt_kernel<<<dim3(2048), dim3(256), 0, stream>>>(W2, Wb);
  moe_gemm3<EXP_D, D_MODEL, true>
      <<<dim3((D_MODEL/256)*MAX_TILES), dim3(512), 147456, stream>>>(
      Hb, Wb, b2, Yb, tileE, meta, slot_w);
  combine_kernel<<<dim3(NTOK), dim3(256), 0, stream>>>(Yb, tok_slot, out);
}

// Round 7
// 708.076 us; speedup vs baseline: 1.2575x; 1.0240x over previous
//
#include <hip/hip_runtime.h>
#include <stdint.h>

#define D_MODEL 1024
#define EXP_D   4096
#define NE      8
#define NTOK    8192
#define BMT     128
#define MAX_TILES 136
#define NS_MAX  17408   // MAX_TILES*128

typedef __attribute__((ext_vector_type(8))) short short8;
typedef __attribute__((ext_vector_type(4))) float f32x4;
typedef __attribute__((ext_vector_type(4))) unsigned short us4;

// ---- workspace layout (bytes) ----
#define WS_COUNTS    0          // int[8]
#define WS_CURSORS   32         // int[8]
#define WS_PADOFF    64         // int[16]
#define WS_META      128        // int[32], meta[0]=ntiles
#define WS_TILE_E    256        // int[256]
#define WS_PP        4096       // float[2048*8]
#define WS_TOP_E     69632      // int[16384]
#define WS_TOP_W     135168     // float[16384]
#define WS_SLOT_W    270336     // float[17408]
#define WS_TOK_SLOT  339968     // int[16384]
#define WS_XG        405504     // bf16 [17408][1024]  (Yb aliases this)
#define WS_HB        36057088   // bf16 [17408][4096]
#define WS_WB        178663424  // bf16 [8][4096][1024] -> ends 245,772,288

__device__ __forceinline__ unsigned short f2bf(float f){
  __bf16 h = (__bf16)f;
  return __builtin_bit_cast(unsigned short, h);
}
__device__ __forceinline__ float bf2f(unsigned short u){
  unsigned int v = ((unsigned int)u) << 16;
  return __builtin_bit_cast(float, v);
}
__device__ __forceinline__ void gl_lds16(const void* g, void* l){
  __builtin_amdgcn_global_load_lds((const __attribute__((address_space(1))) unsigned int*)g,
                                   (__attribute__((address_space(3))) unsigned int*)l,
                                   16, 0, 0);
}

template<int N> __device__ __forceinline__ void vmw(){
  if constexpr (N==0)      asm volatile("s_waitcnt vmcnt(0)" ::: "memory");
  else if constexpr (N==6) asm volatile("s_waitcnt vmcnt(6)" ::: "memory");
}

// ---------------- init: zero 64-int header ----------------
__global__ void init_kernel(int* __restrict__ hdr){
  if (threadIdx.x < 64) hdr[threadIdx.x] = 0;
}

// ---------------- weight fp32 -> bf16 convert ----------------
__global__ __launch_bounds__(256) void cvt_kernel(const float* __restrict__ W,
                                                  unsigned short* __restrict__ Wb){
  const int n4 = NE*EXP_D*D_MODEL/4;
  for (int i = blockIdx.x*256 + threadIdx.x; i < n4; i += gridDim.x*256){
    const float4 v = *(const float4*)&W[(size_t)i*4];
    us4 o; o[0]=f2bf(v.x); o[1]=f2bf(v.y); o[2]=f2bf(v.z); o[3]=f2bf(v.w);
    *(us4*)&Wb[(size_t)i*4] = o;
  }
}

// ---------------- router: one wave per token ----------------
__global__ __launch_bounds__(256) void router_kernel(
    const float* __restrict__ x, const float* __restrict__ Wr,
    const float* __restrict__ br,
    int* __restrict__ counts, int* __restrict__ top_e, float* __restrict__ top_w,
    float* __restrict__ pp)
{
  __shared__ float WrS[NE*D_MODEL];
  __shared__ float wprob[4][NE];
  const int tid = threadIdx.x;
#pragma unroll
  for (int i=0;i<8;++i){
    int j = (tid + i*256)*4;
    *(float4*)&WrS[j] = *(const float4*)&Wr[j];
  }
  __syncthreads();
  const int w = tid>>6, lane = tid&63;
  const int t = blockIdx.x*4 + w;
  const float* xt = x + (size_t)t*D_MODEL;
  float accv[8] = {0,0,0,0,0,0,0,0};
#pragma unroll
  for (int i=0;i<4;++i){
    const int k = i*256 + lane*4;
    const float4 xv = *(const float4*)&xt[k];
#pragma unroll
    for (int e=0;e<8;++e){
      const float4 wv = *(const float4*)&WrS[e*D_MODEL + k];
      accv[e] += xv.x*wv.x + xv.y*wv.y + xv.z*wv.z + xv.w*wv.w;
    }
  }
#pragma unroll
  for (int m=32;m>0;m>>=1){
#pragma unroll
    for (int e=0;e<8;++e) accv[e] += __shfl_xor(accv[e], m, 64);
  }
  if (lane==0){
    float lg[8];
#pragma unroll
    for (int e=0;e<8;++e) lg[e] = accv[e] + br[e];
    float mx = lg[0];
#pragma unroll
    for (int e=1;e<8;++e) mx = fmaxf(mx, lg[e]);
    float p[8]; float s=0.f;
#pragma unroll
    for (int e=0;e<8;++e){ p[e] = __expf(lg[e]-mx); s += p[e]; }
    const float inv = 1.f/s;
#pragma unroll
    for (int e=0;e<8;++e){ p[e] *= inv; wprob[w][e] = p[e]; }
    int i1=0; float p1v=p[0];
#pragma unroll
    for (int e=1;e<8;++e) if (p[e] > p1v){ p1v=p[e]; i1=e; }
    int i2=-1; float p2v=-1.f;
#pragma unroll
    for (int e=0;e<8;++e) if (e!=i1 && p[e] > p2v){ p2v=p[e]; i2=e; }
    const float rn = 1.f/(p1v+p2v);
    top_e[2*t]   = i1; top_w[2*t]   = p1v*rn;
    top_e[2*t+1] = i2; top_w[2*t+1] = p2v*rn;
    atomicAdd(&counts[i1],1);
    atomicAdd(&counts[i2],1);
  }
  __syncthreads();
  if (tid<8){
    pp[blockIdx.x*8+tid] = wprob[0][tid]+wprob[1][tid]+wprob[2][tid]+wprob[3][tid];
  }
}

// ---------------- prefix: tile table + aux loss ----------------
__global__ void prefix_kernel(int* __restrict__ wsI, const float* __restrict__ pp,
                              float* __restrict__ aux_out){
  const int tid = threadIdx.x;
  __shared__ float dev2[8];
  if (tid==0){
    int* counts = wsI + 0;
    int* padoff = wsI + 16;
    int* meta   = wsI + 32;
    int* tileE  = wsI + 64;
    int nt = 0;
    for (int e=0;e<NE;++e){
      padoff[e] = nt*BMT;
      int tiles = (counts[e] + BMT - 1) >> 7;
      for (int i=0;i<tiles;++i) tileE[nt++] = e;
    }
    meta[0] = nt;
  }
  if (tid<8){
    float s=0.f;
    for (int b=0;b<NTOK/4;++b) s += pp[b*8+tid];
    float d = s*(1.f/(float)NTOK) - 0.125f;
    dev2[tid] = d*d;
  }
  __syncthreads();
  if (tid==0){
    float a=0.f;
#pragma unroll
    for (int e=0;e<8;++e) a += dev2[e];
    aux_out[0] = a;
  }
}

// ---------------- scatter: LDS-aggregated atomics ----------------
__global__ __launch_bounds__(1024) void scatter_kernel(
    const int* __restrict__ top_e, const float* __restrict__ top_w,
    int* __restrict__ cursors, const int* __restrict__ padoff,
    float* __restrict__ slot_w, int* __restrict__ tok_slot)
{
  __shared__ int cnt[NE];
  __shared__ int base[NE];
  const int tid = threadIdx.x;
  if (tid < NE) cnt[tid] = 0;
  __syncthreads();
  const int t = blockIdx.x*1024 + tid;
  const int e0 = top_e[2*t], e1 = top_e[2*t+1];
  const float w0v = top_w[2*t], w1v = top_w[2*t+1];
  const int p0 = atomicAdd(&cnt[e0], 1);
  const int p1 = atomicAdd(&cnt[e1], 1);
  __syncthreads();
  if (tid < NE) base[tid] = atomicAdd(&cursors[tid], cnt[tid]);
  __syncthreads();
  const int s0 = padoff[e0] + base[e0] + p0;
  const int s1 = padoff[e1] + base[e1] + p1;
  slot_w[s0] = w0v; slot_w[s1] = w1v;
  tok_slot[2*t] = s0; tok_slot[2*t+1] = s1;
}

// ---------------- gather: wave per token ----------------
__global__ __launch_bounds__(256) void gather_kernel(
    const float* __restrict__ x, const int* __restrict__ tok_slot,
    unsigned short* __restrict__ Xg)
{
  const int w = threadIdx.x>>6, lane = threadIdx.x&63;
  const int t = blockIdx.x*4 + w;
  const int s0 = tok_slot[2*t], s1 = tok_slot[2*t+1];
  us4 o[4];
#pragma unroll
  for (int i=0;i<4;++i){
    const float4 v = *(const float4*)&x[(size_t)t*D_MODEL + i*256 + lane*4];
    o[i][0]=f2bf(v.x); o[i][1]=f2bf(v.y); o[i][2]=f2bf(v.z); o[i][3]=f2bf(v.w);
  }
#pragma unroll
  for (int i=0;i<4;++i) *(us4*)&Xg[(size_t)s0*D_MODEL + i*256 + lane*4] = o[i];
#pragma unroll
  for (int i=0;i<4;++i) *(us4*)&Xg[(size_t)s1*D_MODEL + i*256 + lane*4] = o[i];
}

// ============ grouped GEMM: 128x256 tile, BK=64, 8 waves, 3-buf pipeline ============
// Register-pipelined: ds_reads always overlap an MFMA cluster; ONE barrier per K-tile.
// C[m][n] = sum_k A[m][k] * W[e][n][k]  (+bias; G1: relu; G2: *slot_w[m])
// Buffer (48KB): A rows0-127 @0, B rows0-255 @16384.  Swizzle: chunk ^= row&7 (both sides).
template<int KT, int NT, bool G2>
__global__ __launch_bounds__(512,1) void moe_gemm3(
    const unsigned short* __restrict__ A,
    const unsigned short* __restrict__ Wb,
    const float* __restrict__ bias,
    unsigned short* __restrict__ Cout,
    const int* __restrict__ tileE,
    const int* __restrict__ meta,
    const float* __restrict__ slotw)
{
  constexpr int NX = NT/256;
  constexpr int TOTAL = NX*MAX_TILES;
  constexpr int Q = TOTAL/8, R = TOTAL%8;
  constexpr int NTILES = KT/64;
  constexpr int K3 = (NTILES-4)/3;
  static_assert((NTILES-4)%3 == 0, "tail peel needs (NTILES-4)%3==0");

  const int lid = blockIdx.x;
  const int xcc = lid & 7, jj = lid >> 3;
  const int tsw = xcc*Q + (xcc < R ? xcc : R) + jj;
  const int mtile = tsw / NX, ntile = tsw - mtile*NX;
  if (mtile >= meta[0]) return;

  extern __shared__ char smem[];
  char* const BUF0 = smem;
  char* const BUF1 = smem + 49152;
  char* const BUF2 = smem + 98304;

  const int tid = threadIdx.x;
  const int w = tid>>6, lane = tid&63;
  const int wr = w>>2, wn = w&3;
  const int r15 = lane&15, kg = lane>>4;
  const int e  = tileE[mtile];
  const int m0 = mtile*BMT;
  const int n0 = ntile*256;

  // staging source (pre-swizzled global chunk: phys chunk t&7 holds logical (t&7)^(row&7))
  const int trow = tid>>3;
  const int tch  = ((tid&7) ^ (trow&7))*8;
  const unsigned short* sA = A  + (size_t)(m0 + trow)*KT + tch;
  const unsigned short* sB = Wb + (size_t)e*NT*KT + (size_t)(n0 + trow)*KT + tch;

#define STG_ALL(BS, KTT) do{ \
    gl_lds16(sA + (size_t)(KTT)*64,                  (BS) + tid*16); \
    gl_lds16(sA + (size_t)(KTT)*64 + (size_t)64*KT,  (BS) + 8192  + tid*16); \
    gl_lds16(sB + (size_t)(KTT)*64,                  (BS) + 16384 + tid*16); \
    gl_lds16(sB + (size_t)(KTT)*64 + (size_t)64*KT,  (BS) + 24576 + tid*16); \
    gl_lds16(sB + (size_t)(KTT)*64 + (size_t)128*KT, (BS) + 32768 + tid*16); \
    gl_lds16(sB + (size_t)(KTT)*64 + (size_t)192*KT, (BS) + 40960 + tid*16); \
  }while(0)

  // fragment read byte-offsets (ks=0); ks=1 = offset ^ 64 (chunk ^= 4)
  const int key4 = (kg ^ (r15&7))<<4;
  const int a0 = (wr*64 + 0*16 + r15)*128 + key4;
  const int a1 = (wr*64 + 1*16 + r15)*128 + key4;
  const int a2 = (wr*64 + 2*16 + r15)*128 + key4;
  const int a3 = (wr*64 + 3*16 + r15)*128 + key4;
  const int b0 = 16384 + (wn*64 + 0*16 + r15)*128 + key4;
  const int b1 = 16384 + (wn*64 + 1*16 + r15)*128 + key4;
  const int b2 = 16384 + (wn*64 + 2*16 + r15)*128 + key4;
  const int b3 = 16384 + (wn*64 + 3*16 + r15)*128 + key4;

  f32x4 acc[4][4];
#pragma unroll
  for (int i=0;i<4;++i)
#pragma unroll
    for (int j=0;j<4;++j) acc[i][j] = (f32x4){0.f,0.f,0.f,0.f};

  short8 A0[4], B0[4], A1[4], B1[4];

#define MFMA16(AX, BX) \
    acc[0][0]=__builtin_amdgcn_mfma_f32_16x16x32_bf16(BX[0],AX[0],acc[0][0],0,0,0); \
    acc[0][1]=__builtin_amdgcn_mfma_f32_16x16x32_bf16(BX[1],AX[0],acc[0][1],0,0,0); \
    acc[0][2]=__builtin_amdgcn_mfma_f32_16x16x32_bf16(BX[2],AX[0],acc[0][2],0,0,0); \
    acc[0][3]=__builtin_amdgcn_mfma_f32_16x16x32_bf16(BX[3],AX[0],acc[0][3],0,0,0); \
    acc[1][0]=__builtin_amdgcn_mfma_f32_16x16x32_bf16(BX[0],AX[1],acc[1][0],0,0,0); \
    acc[1][1]=__builtin_amdgcn_mfma_f32_16x16x32_bf16(BX[1],AX[1],acc[1][1],0,0,0); \
    acc[1][2]=__builtin_amdgcn_mfma_f32_16x16x32_bf16(BX[2],AX[1],acc[1][2],0,0,0); \
    acc[1][3]=__builtin_amdgcn_mfma_f32_16x16x32_bf16(BX[3],AX[1],acc[1][3],0,0,0); \
    acc[2][0]=__builtin_amdgcn_mfma_f32_16x16x32_bf16(BX[0],AX[2],acc[2][0],0,0,0); \
    acc[2][1]=__builtin_amdgcn_mfma_f32_16x16x32_bf16(BX[1],AX[2],acc[2][1],0,0,0); \
    acc[2][2]=__builtin_amdgcn_mfma_f32_16x16x32_bf16(BX[2],AX[2],acc[2][2],0,0,0); \
    acc[2][3]=__builtin_amdgcn_mfma_f32_16x16x32_bf16(BX[3],AX[2],acc[2][3],0,0,0); \
    acc[3][0]=__builtin_amdgcn_mfma_f32_16x16x32_bf16(BX[0],AX[3],acc[3][0],0,0,0); \
    acc[3][1]=__builtin_amdgcn_mfma_f32_16x16x32_bf16(BX[1],AX[3],acc[3][1],0,0,0); \
    acc[3][2]=__builtin_amdgcn_mfma_f32_16x16x32_bf16(BX[2],AX[3],acc[3][2],0,0,0); \
    acc[3][3]=__builtin_amdgcn_mfma_f32_16x16x32_bf16(BX[3],AX[3],acc[3][3],0,0,0);

#define RD_KS1(BC) do{ \
    A1[0] = *(const short8*)((BC) + (a0 ^ 64)); \
    A1[1] = *(const short8*)((BC) + (a1 ^ 64)); \
    A1[2] = *(const short8*)((BC) + (a2 ^ 64)); \
    A1[3] = *(const short8*)((BC) + (a3 ^ 64)); \
    B1[0] = *(const short8*)((BC) + (b0 ^ 64)); \
    B1[1] = *(const short8*)((BC) + (b1 ^ 64)); \
    B1[2] = *(const short8*)((BC) + (b2 ^ 64)); \
    B1[3] = *(const short8*)((BC) + (b3 ^ 64)); \
  }while(0)
#define RD_KS0(BN1) do{ \
    A0[0] = *(const short8*)((BN1) + a0); \
    A0[1] = *(const short8*)((BN1) + a1); \
    A0[2] = *(const short8*)((BN1) + a2); \
    A0[3] = *(const short8*)((BN1) + a3); \
    B0[0] = *(const short8*)((BN1) + b0); \
    B0[1] = *(const short8*)((BN1) + b1); \
    B0[2] = *(const short8*)((BN1) + b2); \
    B0[3] = *(const short8*)((BN1) + b3); \
  }while(0)

// one K-tile, ONE barrier. ks1-reads + next-stage overlap MFMA ks0;
// next-tile ks0-reads overlap MFMA ks1. lgkm0 before barrier = cross-wave
// read-before-overwrite safety for the buffer staged next tile.
#define TILE(BC, BN1, STG_STMT, VM_STMT) do{ \
    RD_KS1(BC); \
    STG_STMT; \
    __builtin_amdgcn_sched_barrier(0); \
    __builtin_amdgcn_s_setprio(1); \
    MFMA16(A0, B0) \
    __builtin_amdgcn_s_setprio(0); \
    __builtin_amdgcn_sched_barrier(0); \
    VM_STMT; \
    asm volatile("s_waitcnt lgkmcnt(0)" ::: "memory"); \
    __builtin_amdgcn_sched_barrier(0); \
    __builtin_amdgcn_s_barrier(); \
    RD_KS0(BN1); \
    __builtin_amdgcn_sched_barrier(0); \
    __builtin_amdgcn_s_setprio(1); \
    MFMA16(A1, B1) \
    __builtin_amdgcn_s_setprio(0); \
    __builtin_amdgcn_sched_barrier(0); \
  }while(0)

  // prologue: stage tiles 0 (buf0) and 1 (buf1); wait tile 0; preload ks0 frags
  STG_ALL(BUF0, 0);
  STG_ALL(BUF1, 1);
  vmw<6>();
  __builtin_amdgcn_s_barrier();
  RD_KS0(BUF0);

#pragma unroll 1
  for (int i = 0; i < K3; ++i){
    const int kt = i*3;
    TILE(BUF0, BUF1, STG_ALL(BUF2, kt+2), vmw<6>());
    TILE(BUF1, BUF2, STG_ALL(BUF0, kt+3), vmw<6>());
    TILE(BUF2, BUF0, STG_ALL(BUF1, kt+4), vmw<6>());
  }
  // tiles NTILES-4, NTILES-3 (steady, stage last two K-tiles)
  TILE(BUF0, BUF1, STG_ALL(BUF2, NTILES-2), vmw<6>());
  TILE(BUF1, BUF2, STG_ALL(BUF0, NTILES-1), vmw<6>());
  // tile NTILES-2: no stage; drain tile NTILES-1's loads
  TILE(BUF2, BUF0, (void)0, vmw<0>());
  { // tile NTILES-1 (buf0): final, no stage/barrier
    RD_KS1(BUF0);
    __builtin_amdgcn_sched_barrier(0);
    __builtin_amdgcn_s_setprio(1);
    MFMA16(A0, B0)
    __builtin_amdgcn_s_setprio(0);
    __builtin_amdgcn_sched_barrier(0);
    __builtin_amdgcn_s_setprio(1);
    MFMA16(A1, B1)
    __builtin_amdgcn_s_setprio(0);
  }
#undef TILE
#undef RD_KS0
#undef RD_KS1
#undef MFMA16
#undef STG_ALL

  // epilogue: lane r15 <-> m, (lane>>4)*4 + reg <-> n  (verified layout)
  const int ng4 = kg*4;
#pragma unroll
  for (int mf=0; mf<4; ++mf){
    const int m = m0 + wr*64 + mf*16 + r15;
    float wg = 0.f;
    if (G2) wg = slotw[m];
#pragma unroll
    for (int nf=0; nf<4; ++nf){
      const int nb = n0 + wn*64 + nf*16 + ng4;
      const float4 bv = *(const float4*)&bias[(size_t)e*NT + nb];
      float q0 = acc[mf][nf][0] + bv.x;
      float q1 = acc[mf][nf][1] + bv.y;
      float q2 = acc[mf][nf][2] + bv.z;
      float q3 = acc[mf][nf][3] + bv.w;
      if (!G2){
        q0=fmaxf(q0,0.f); q1=fmaxf(q1,0.f); q2=fmaxf(q2,0.f); q3=fmaxf(q3,0.f);
      } else {
        q0*=wg; q1*=wg; q2*=wg; q3*=wg;
      }
      us4 o; o[0]=f2bf(q0); o[1]=f2bf(q1); o[2]=f2bf(q2); o[3]=f2bf(q3);
      *(us4*)&Cout[(size_t)m*NT + nb] = o;
    }
  }
}

// ---------------- combine: out[t] = Y[slot0] + Y[slot1] ----------------
__global__ __launch_bounds__(256) void combine_kernel(
    const unsigned short* __restrict__ Yb, const int* __restrict__ tok_slot,
    float* __restrict__ out)
{
  const int t = blockIdx.x;
  const int tid = threadIdx.x;
  const int s0 = tok_slot[2*t], s1 = tok_slot[2*t+1];
  const us4 a = *(const us4*)&Yb[(size_t)s0*D_MODEL + tid*4];
  const us4 b = *(const us4*)&Yb[(size_t)s1*D_MODEL + tid*4];
  float4 o;
  o.x = bf2f(a[0]) + bf2f(b[0]);
  o.y = bf2f(a[1]) + bf2f(b[1]);
  o.z = bf2f(a[2]) + bf2f(b[2]);
  o.w = bf2f(a[3]) + bf2f(b[3]);
  *(float4*)&out[(size_t)t*D_MODEL + tid*4] = o;
}

extern "C" void kernel_launch(void* const* d_in, const int* in_sizes, int n_in,
                              void* d_out, int out_size, void* d_ws, size_t ws_size,
                              hipStream_t stream)
{
  const float* x  = (const float*)d_in[0];
  const float* Wr = (const float*)d_in[1];
  const float* br = (const float*)d_in[2];
  const float* W1 = (const float*)d_in[3];
  const float* b1 = (const float*)d_in[4];
  const float* W2 = (const float*)d_in[5];
  const float* b2 = (const float*)d_in[6];
  float* out = (float*)d_out;
  char* ws = (char*)d_ws;

  int*   counts  = (int*)(ws + WS_COUNTS);
  int*   cursors = (int*)(ws + WS_CURSORS);
  int*   padoff  = (int*)(ws + WS_PADOFF);
  int*   meta    = (int*)(ws + WS_META);
  int*   tileE   = (int*)(ws + WS_TILE_E);
  float* pp      = (float*)(ws + WS_PP);
  int*   top_e   = (int*)(ws + WS_TOP_E);
  float* top_w   = (float*)(ws + WS_TOP_W);
  float* slot_w  = (float*)(ws + WS_SLOT_W);
  int*   tok_slot= (int*)(ws + WS_TOK_SLOT);
  unsigned short* Xg = (unsigned short*)(ws + WS_XG);
  unsigned short* Hb = (unsigned short*)(ws + WS_HB);
  unsigned short* Wb = (unsigned short*)(ws + WS_WB);
  unsigned short* Yb = Xg;   // Xg dead after GEMM1

  hipFuncSetAttribute((const void*)moe_gemm3<D_MODEL, EXP_D, false>,
                      hipFuncAttributeMaxDynamicSharedMemorySize, 147456);
  hipFuncSetAttribute((const void*)moe_gemm3<EXP_D, D_MODEL, true>,
                      hipFuncAttributeMaxDynamicSharedMemorySize, 147456);

  init_kernel<<<dim3(1), dim3(64), 0, stream>>>((int*)ws);
  router_kernel<<<dim3(NTOK/4), dim3(256), 0, stream>>>(x, Wr, br, counts, top_e, top_w, pp);
  prefix_kernel<<<dim3(1), dim3(256), 0, stream>>>((int*)ws, pp, out + (size_t)NTOK*D_MODEL);
  scatter_kernel<<<dim3(NTOK/1024), dim3(1024), 0, stream>>>(top_e, top_w, cursors, padoff,
                                                             slot_w, tok_slot);
  gather_kernel<<<dim3(NTOK/4), dim3(256), 0, stream>>>(x, tok_slot, Xg);
  cvt_kernel<<<dim3(2048), dim3(256), 0, stream>>>(W1, Wb);
  moe_gemm3<D_MODEL, EXP_D, false>
      <<<dim3((EXP_D/256)*MAX_TILES), dim3(512), 147456, stream>>>(
      Xg, Wb, b1, Hb, tileE, meta, slot_w);
  cvt_kernel<<<dim3(2048), dim3(256), 0, stream>>>(W2, Wb);
  moe_gemm3<EXP_D, D_MODEL, true>
      <<<dim3((D_MODEL/256)*MAX_TILES), dim3(512), 147456, stream>>>(
      Hb, Wb, b2, Yb, tileE, meta, slot_w);
  combine_kernel<<<dim3(NTOK), dim3(256), 0, stream>>>(Yb, tok_slot, out);
}

// Round 8
// 678.161 us; speedup vs baseline: 1.3130x; 1.0441x over previous
//
#include <hip/hip_runtime.h>
#include <stdint.h>

#define D_MODEL 1024
#define EXP_D   4096
#define NE      8
#define NTOK    8192
#define BMT     128
#define MAX_TILES 136
#define NS_MAX  17408   // MAX_TILES*128

typedef __attribute__((ext_vector_type(8))) short short8;
typedef __attribute__((ext_vector_type(4))) float f32x4;
typedef __attribute__((ext_vector_type(4))) unsigned short us4;

// ---- workspace layout (bytes) ----
#define WS_COUNTS    0          // int[8]
#define WS_CURSORS   32         // int[8]
#define WS_PADOFF    64         // int[16]
#define WS_META      128        // int[32], meta[0]=ntiles
#define WS_TILE_E    256        // int[256]
#define WS_PP        4096       // float[2048*8]
#define WS_TOP_E     69632      // int[16384]
#define WS_TOP_W     135168     // float[16384]
#define WS_SLOT_W    270336     // float[17408]
#define WS_TOK_SLOT  339968     // int[16384]
#define WS_XG        405504     // bf16 [17408][1024]  (Yb aliases this)
#define WS_HB        36057088   // bf16 [17408][4096]
#define WS_WB        178663424  // bf16 [8][4096][1024] -> ends 245,772,288

__device__ __forceinline__ unsigned short f2bf(float f){
  __bf16 h = (__bf16)f;
  return __builtin_bit_cast(unsigned short, h);
}
__device__ __forceinline__ float bf2f(unsigned short u){
  unsigned int v = ((unsigned int)u) << 16;
  return __builtin_bit_cast(float, v);
}
__device__ __forceinline__ void gl_lds16(const void* g, void* l){
  __builtin_amdgcn_global_load_lds((const __attribute__((address_space(1))) unsigned int*)g,
                                   (__attribute__((address_space(3))) unsigned int*)l,
                                   16, 0, 0);
}

template<int N> __device__ __forceinline__ void vmw(){
  if constexpr (N==0)      asm volatile("s_waitcnt vmcnt(0)" ::: "memory");
  else if constexpr (N==6) asm volatile("s_waitcnt vmcnt(6)" ::: "memory");
}

// ---------------- router (blocks 0..2047) + W1 cvt (blocks 2048..4095) ----------------
__global__ __launch_bounds__(256) void router_cvt_kernel(
    const float* __restrict__ x, const float* __restrict__ Wr,
    const float* __restrict__ br,
    int* __restrict__ counts, int* __restrict__ top_e, float* __restrict__ top_w,
    float* __restrict__ pp,
    const float* __restrict__ W1, unsigned short* __restrict__ Wb)
{
  const int tid = threadIdx.x;
  if ((int)blockIdx.x >= NTOK/4){
    const int n4 = NE*EXP_D*D_MODEL/4;
    for (int i = ((int)blockIdx.x - NTOK/4)*256 + tid; i < n4; i += 2048*256){
      const float4 v = *(const float4*)&W1[(size_t)i*4];
      us4 o; o[0]=f2bf(v.x); o[1]=f2bf(v.y); o[2]=f2bf(v.z); o[3]=f2bf(v.w);
      *(us4*)&Wb[(size_t)i*4] = o;
    }
    return;
  }
  __shared__ float WrS[NE*D_MODEL];
  __shared__ float wprob[4][NE];
#pragma unroll
  for (int i=0;i<8;++i){
    int j = (tid + i*256)*4;
    *(float4*)&WrS[j] = *(const float4*)&Wr[j];
  }
  __syncthreads();
  const int w = tid>>6, lane = tid&63;
  const int t = blockIdx.x*4 + w;
  const float* xt = x + (size_t)t*D_MODEL;
  float accv[8] = {0,0,0,0,0,0,0,0};
#pragma unroll
  for (int i=0;i<4;++i){
    const int k = i*256 + lane*4;
    const float4 xv = *(const float4*)&xt[k];
#pragma unroll
    for (int e=0;e<8;++e){
      const float4 wv = *(const float4*)&WrS[e*D_MODEL + k];
      accv[e] += xv.x*wv.x + xv.y*wv.y + xv.z*wv.z + xv.w*wv.w;
    }
  }
#pragma unroll
  for (int m=32;m>0;m>>=1){
#pragma unroll
    for (int e=0;e<8;++e) accv[e] += __shfl_xor(accv[e], m, 64);
  }
  if (lane==0){
    float lg[8];
#pragma unroll
    for (int e=0;e<8;++e) lg[e] = accv[e] + br[e];
    float mx = lg[0];
#pragma unroll
    for (int e=1;e<8;++e) mx = fmaxf(mx, lg[e]);
    float p[8]; float s=0.f;
#pragma unroll
    for (int e=0;e<8;++e){ p[e] = __expf(lg[e]-mx); s += p[e]; }
    const float inv = 1.f/s;
#pragma unroll
    for (int e=0;e<8;++e){ p[e] *= inv; wprob[w][e] = p[e]; }
    int i1=0; float p1v=p[0];
#pragma unroll
    for (int e=1;e<8;++e) if (p[e] > p1v){ p1v=p[e]; i1=e; }
    int i2=-1; float p2v=-1.f;
#pragma unroll
    for (int e=0;e<8;++e) if (e!=i1 && p[e] > p2v){ p2v=p[e]; i2=e; }
    const float rn = 1.f/(p1v+p2v);
    top_e[2*t]   = i1; top_w[2*t]   = p1v*rn;
    top_e[2*t+1] = i2; top_w[2*t+1] = p2v*rn;
    atomicAdd(&counts[i1],1);
    atomicAdd(&counts[i2],1);
  }
  __syncthreads();
  if (tid<8){
    pp[blockIdx.x*8+tid] = wprob[0][tid]+wprob[1][tid]+wprob[2][tid]+wprob[3][tid];
  }
}

// ---------------- weight fp32 -> bf16 convert (standalone, for W2) ----------------
__global__ __launch_bounds__(256) void cvt_kernel(const float* __restrict__ W,
                                                  unsigned short* __restrict__ Wb){
  const int n4 = NE*EXP_D*D_MODEL/4;
  for (int i = blockIdx.x*256 + threadIdx.x; i < n4; i += gridDim.x*256){
    const float4 v = *(const float4*)&W[(size_t)i*4];
    us4 o; o[0]=f2bf(v.x); o[1]=f2bf(v.y); o[2]=f2bf(v.z); o[3]=f2bf(v.w);
    *(us4*)&Wb[(size_t)i*4] = o;
  }
}

// ---------------- prefix: parallel tile table + aux loss ----------------
__global__ __launch_bounds__(256) void prefix_kernel(int* __restrict__ wsI,
                                                     const float* __restrict__ pp,
                                                     float* __restrict__ aux_out){
  const int tid = threadIdx.x;
  int* counts = wsI + 0;
  int* padoff = wsI + 16;
  int* meta   = wsI + 32;
  int* tileE  = wsI + 64;
  __shared__ int tileCum[9];
  __shared__ float dev2[8];
  if (tid==0){
    int nt = 0;
    tileCum[0] = 0;
    for (int e=0;e<NE;++e){
      padoff[e] = nt*BMT;
      nt += (counts[e] + BMT - 1) >> 7;
      tileCum[e+1] = nt;
    }
    meta[0] = nt;
  }
  __syncthreads();
  const int nt = tileCum[8];
  for (int i=tid; i<nt; i+=256){
    int e = 0;
    while (tileCum[e+1] <= i) ++e;
    tileE[i] = e;
  }
  // aux: 8 experts x 32 threads strided partial sums, shfl-reduce
  const int ex = tid>>5, j = tid&31;
  float s = 0.f;
  for (int b=j; b<NTOK/4; b+=32) s += pp[b*8+ex];
#pragma unroll
  for (int m=16;m>0;m>>=1) s += __shfl_xor(s, m, 64);
  if (j==0){ float d = s*(1.f/(float)NTOK) - 0.125f; dev2[ex] = d*d; }
  __syncthreads();
  if (tid==0){
    float a=0.f;
#pragma unroll
    for (int e=0;e<8;++e) a += dev2[e];
    aux_out[0] = a;
  }
}

// ---------------- scatter: LDS-aggregated atomics ----------------
__global__ __launch_bounds__(1024) void scatter_kernel(
    const int* __restrict__ top_e, const float* __restrict__ top_w,
    int* __restrict__ cursors, const int* __restrict__ padoff,
    float* __restrict__ slot_w, int* __restrict__ tok_slot)
{
  __shared__ int cnt[NE];
  __shared__ int base[NE];
  const int tid = threadIdx.x;
  if (tid < NE) cnt[tid] = 0;
  __syncthreads();
  const int t = blockIdx.x*1024 + tid;
  const int e0 = top_e[2*t], e1 = top_e[2*t+1];
  const float w0v = top_w[2*t], w1v = top_w[2*t+1];
  const int p0 = atomicAdd(&cnt[e0], 1);
  const int p1 = atomicAdd(&cnt[e1], 1);
  __syncthreads();
  if (tid < NE) base[tid] = atomicAdd(&cursors[tid], cnt[tid]);
  __syncthreads();
  const int s0 = padoff[e0] + base[e0] + p0;
  const int s1 = padoff[e1] + base[e1] + p1;
  slot_w[s0] = w0v; slot_w[s1] = w1v;
  tok_slot[2*t] = s0; tok_slot[2*t+1] = s1;
}

// ---------------- gather: wave per token ----------------
__global__ __launch_bounds__(256) void gather_kernel(
    const float* __restrict__ x, const int* __restrict__ tok_slot,
    unsigned short* __restrict__ Xg)
{
  const int w = threadIdx.x>>6, lane = threadIdx.x&63;
  const int t = blockIdx.x*4 + w;
  const int s0 = tok_slot[2*t], s1 = tok_slot[2*t+1];
  us4 o[4];
#pragma unroll
  for (int i=0;i<4;++i){
    const float4 v = *(const float4*)&x[(size_t)t*D_MODEL + i*256 + lane*4];
    o[i][0]=f2bf(v.x); o[i][1]=f2bf(v.y); o[i][2]=f2bf(v.z); o[i][3]=f2bf(v.w);
  }
#pragma unroll
  for (int i=0;i<4;++i) *(us4*)&Xg[(size_t)s0*D_MODEL + i*256 + lane*4] = o[i];
#pragma unroll
  for (int i=0;i<4;++i) *(us4*)&Xg[(size_t)s1*D_MODEL + i*256 + lane*4] = o[i];
}

// ============ GEMM1: 128x512 tile, BK=64, 8 waves (wave tile 128x64), 2-buf 160KB ============
template<int KT, int NT, bool G2>
__global__ __launch_bounds__(512,1) void moe_gemm_w(
    const unsigned short* __restrict__ A,
    const unsigned short* __restrict__ Wb,
    const float* __restrict__ bias,
    unsigned short* __restrict__ Cout,
    const int* __restrict__ tileE,
    const int* __restrict__ meta,
    const float* __restrict__ slotw)
{
  constexpr int NX = NT/512;
  constexpr int TOTAL = NX*MAX_TILES;
  constexpr int Q = TOTAL/8, R = TOTAL%8;
  constexpr int NTILES = KT/64;
  static_assert(NTILES%2==0, "even K-tiles");

  const int lid = blockIdx.x;
  const int xcc = lid & 7, jj = lid >> 3;
  const int tsw = xcc*Q + (xcc < R ? xcc : R) + jj;
  const int mtile = tsw / NX, ntile = tsw - mtile*NX;
  if (mtile >= meta[0]) return;

  extern __shared__ char smem[];
  char* const BUF0 = smem;
  char* const BUF1 = smem + 81920;

  const int tid = threadIdx.x;
  const int w = tid>>6, lane = tid&63;
  const int r15 = lane&15, kg = lane>>4;
  const int e  = tileE[mtile];
  const int m0 = mtile*BMT;
  const int n0 = ntile*512;

  // staging (pre-swizzled global chunk)
  const int trow = tid>>3;
  const int tch  = ((tid&7) ^ (trow&7))*8;
  const unsigned short* sA = A  + (size_t)(m0 + trow)*KT + tch;
  const unsigned short* sB = Wb + (size_t)e*NT*KT + (size_t)(n0 + trow)*KT + tch;

#define WSTG(BS, KTT) do{ \
    gl_lds16(sA + (size_t)(KTT)*64,                  (BS) + tid*16); \
    gl_lds16(sA + (size_t)(KTT)*64 + (size_t)64*KT,  (BS) + 8192 + tid*16); \
    _Pragma("unroll") \
    for (int jq=0;jq<8;++jq) \
      gl_lds16(sB + (size_t)(KTT)*64 + (size_t)(64*jq)*KT, (BS) + 16384 + jq*8192 + tid*16); \
  }while(0)

  const int key4  = (kg ^ (r15&7))<<4;
  const int abase = r15*128 + key4;
  const int bbase = 16384 + w*8192 + r15*128 + key4;

  f32x4 acc[8][4];
#pragma unroll
  for (int i=0;i<8;++i)
#pragma unroll
    for (int j=0;j<4;++j) acc[i][j] = (f32x4){0.f,0.f,0.f,0.f};

  short8 A0[8], A1[8], B0[4], B1[4];

#define RD0(BB) do{ const char* pa=(BB)+abase; const char* pb=(BB)+bbase; \
  _Pragma("unroll") for(int q=0;q<8;++q) A0[q]=*(const short8*)(pa+q*2048); \
  _Pragma("unroll") for(int q=0;q<4;++q) B0[q]=*(const short8*)(pb+q*2048); }while(0)
#define RD1(BB) do{ const char* pa=(BB)+(abase^64); const char* pb=(BB)+(bbase^64); \
  _Pragma("unroll") for(int q=0;q<8;++q) A1[q]=*(const short8*)(pa+q*2048); \
  _Pragma("unroll") for(int q=0;q<4;++q) B1[q]=*(const short8*)(pb+q*2048); }while(0)

#define MM32(AX,BX) do{ \
  _Pragma("unroll") for(int mi=0;mi<8;++mi) \
  _Pragma("unroll") for(int nf=0;nf<4;++nf) \
    acc[mi][nf]=__builtin_amdgcn_mfma_f32_16x16x32_bf16(BX[nf],AX[mi],acc[mi][nf],0,0,0); \
}while(0)

// one K-tile, one barrier; stage next into BN1; vmcnt(0) after a full MFMA cluster
#define WTILE(BC,BN1,STG_STMT) do{ \
  RD1(BC); \
  STG_STMT; \
  __builtin_amdgcn_sched_barrier(0); \
  __builtin_amdgcn_s_setprio(1); MM32(A0,B0); __builtin_amdgcn_s_setprio(0); \
  __builtin_amdgcn_sched_barrier(0); \
  asm volatile("s_waitcnt vmcnt(0)" ::: "memory"); \
  asm volatile("s_waitcnt lgkmcnt(0)" ::: "memory"); \
  __builtin_amdgcn_sched_barrier(0); \
  __builtin_amdgcn_s_barrier(); \
  RD0(BN1); \
  __builtin_amdgcn_sched_barrier(0); \
  __builtin_amdgcn_s_setprio(1); MM32(A1,B1); __builtin_amdgcn_s_setprio(0); \
  __builtin_amdgcn_sched_barrier(0); \
}while(0)

  // prologue
  WSTG(BUF0, 0);
  asm volatile("s_waitcnt vmcnt(0)" ::: "memory");
  __builtin_amdgcn_s_barrier();
  RD0(BUF0);

#pragma unroll 1
  for (int i = 0; i < (NTILES-2)/2; ++i){
    WTILE(BUF0, BUF1, WSTG(BUF1, 2*i+1));
    WTILE(BUF1, BUF0, WSTG(BUF0, 2*i+2));
  }
  WTILE(BUF0, BUF1, WSTG(BUF1, NTILES-1));   // tile NTILES-2
  { // tile NTILES-1 (BUF1): final
    RD1(BUF1);
    __builtin_amdgcn_sched_barrier(0);
    __builtin_amdgcn_s_setprio(1); MM32(A0,B0); __builtin_amdgcn_s_setprio(0);
    asm volatile("s_waitcnt lgkmcnt(0)" ::: "memory");
    __builtin_amdgcn_sched_barrier(0);
    __builtin_amdgcn_s_setprio(1); MM32(A1,B1); __builtin_amdgcn_s_setprio(0);
  }
#undef WTILE
#undef MM32
#undef RD0
#undef RD1
#undef WSTG

  // epilogue: m = m0 + mi*16 + r15; n = n0 + w*64 + nf*16 + kg*4 + reg
  const int ng4 = kg*4;
#pragma unroll
  for (int mi=0; mi<8; ++mi){
    const int m = m0 + mi*16 + r15;
    float wg = 0.f;
    if (G2) wg = slotw[m];
#pragma unroll
    for (int nf=0; nf<4; ++nf){
      const int nb = n0 + w*64 + nf*16 + ng4;
      const float4 bv = *(const float4*)&bias[(size_t)e*NT + nb];
      float q0 = acc[mi][nf][0] + bv.x;
      float q1 = acc[mi][nf][1] + bv.y;
      float q2 = acc[mi][nf][2] + bv.z;
      float q3 = acc[mi][nf][3] + bv.w;
      if (!G2){
        q0=fmaxf(q0,0.f); q1=fmaxf(q1,0.f); q2=fmaxf(q2,0.f); q3=fmaxf(q3,0.f);
      } else {
        q0*=wg; q1*=wg; q2*=wg; q3*=wg;
      }
      us4 o; o[0]=f2bf(q0); o[1]=f2bf(q1); o[2]=f2bf(q2); o[3]=f2bf(q3);
      *(us4*)&Cout[(size_t)m*NT + nb] = o;
    }
  }
}

// ============ GEMM2 (unchanged round-7): 128x256, BK=64, 8 waves, 3-buf pipeline ============
template<int KT, int NT, bool G2>
__global__ __launch_bounds__(512,1) void moe_gemm3(
    const unsigned short* __restrict__ A,
    const unsigned short* __restrict__ Wb,
    const float* __restrict__ bias,
    unsigned short* __restrict__ Cout,
    const int* __restrict__ tileE,
    const int* __restrict__ meta,
    const float* __restrict__ slotw)
{
  constexpr int NX = NT/256;
  constexpr int TOTAL = NX*MAX_TILES;
  constexpr int Q = TOTAL/8, R = TOTAL%8;
  constexpr int NTILES = KT/64;
  constexpr int K3 = (NTILES-4)/3;
  static_assert((NTILES-4)%3 == 0, "tail peel needs (NTILES-4)%3==0");

  const int lid = blockIdx.x;
  const int xcc = lid & 7, jj = lid >> 3;
  const int tsw = xcc*Q + (xcc < R ? xcc : R) + jj;
  const int mtile = tsw / NX, ntile = tsw - mtile*NX;
  if (mtile >= meta[0]) return;

  extern __shared__ char smem[];
  char* const BUF0 = smem;
  char* const BUF1 = smem + 49152;
  char* const BUF2 = smem + 98304;

  const int tid = threadIdx.x;
  const int w = tid>>6, lane = tid&63;
  const int wr = w>>2, wn = w&3;
  const int r15 = lane&15, kg = lane>>4;
  const int e  = tileE[mtile];
  const int m0 = mtile*BMT;
  const int n0 = ntile*256;

  const int trow = tid>>3;
  const int tch  = ((tid&7) ^ (trow&7))*8;
  const unsigned short* sA = A  + (size_t)(m0 + trow)*KT + tch;
  const unsigned short* sB = Wb + (size_t)e*NT*KT + (size_t)(n0 + trow)*KT + tch;

#define STG_ALL(BS, KTT) do{ \
    gl_lds16(sA + (size_t)(KTT)*64,                  (BS) + tid*16); \
    gl_lds16(sA + (size_t)(KTT)*64 + (size_t)64*KT,  (BS) + 8192  + tid*16); \
    gl_lds16(sB + (size_t)(KTT)*64,                  (BS) + 16384 + tid*16); \
    gl_lds16(sB + (size_t)(KTT)*64 + (size_t)64*KT,  (BS) + 24576 + tid*16); \
    gl_lds16(sB + (size_t)(KTT)*64 + (size_t)128*KT, (BS) + 32768 + tid*16); \
    gl_lds16(sB + (size_t)(KTT)*64 + (size_t)192*KT, (BS) + 40960 + tid*16); \
  }while(0)

  const int key4 = (kg ^ (r15&7))<<4;
  const int a0 = (wr*64 + 0*16 + r15)*128 + key4;
  const int a1 = (wr*64 + 1*16 + r15)*128 + key4;
  const int a2 = (wr*64 + 2*16 + r15)*128 + key4;
  const int a3 = (wr*64 + 3*16 + r15)*128 + key4;
  const int b0 = 16384 + (wn*64 + 0*16 + r15)*128 + key4;
  const int b1 = 16384 + (wn*64 + 1*16 + r15)*128 + key4;
  const int b2 = 16384 + (wn*64 + 2*16 + r15)*128 + key4;
  const int b3 = 16384 + (wn*64 + 3*16 + r15)*128 + key4;

  f32x4 acc[4][4];
#pragma unroll
  for (int i=0;i<4;++i)
#pragma unroll
    for (int j=0;j<4;++j) acc[i][j] = (f32x4){0.f,0.f,0.f,0.f};

  short8 A0[4], B0[4], A1[4], B1[4];

#define MFMA16(AX, BX) \
    acc[0][0]=__builtin_amdgcn_mfma_f32_16x16x32_bf16(BX[0],AX[0],acc[0][0],0,0,0); \
    acc[0][1]=__builtin_amdgcn_mfma_f32_16x16x32_bf16(BX[1],AX[0],acc[0][1],0,0,0); \
    acc[0][2]=__builtin_amdgcn_mfma_f32_16x16x32_bf16(BX[2],AX[0],acc[0][2],0,0,0); \
    acc[0][3]=__builtin_amdgcn_mfma_f32_16x16x32_bf16(BX[3],AX[0],acc[0][3],0,0,0); \
    acc[1][0]=__builtin_amdgcn_mfma_f32_16x16x32_bf16(BX[0],AX[1],acc[1][0],0,0,0); \
    acc[1][1]=__builtin_amdgcn_mfma_f32_16x16x32_bf16(BX[1],AX[1],acc[1][1],0,0,0); \
    acc[1][2]=__builtin_amdgcn_mfma_f32_16x16x32_bf16(BX[2],AX[1],acc[1][2],0,0,0); \
    acc[1][3]=__builtin_amdgcn_mfma_f32_16x16x32_bf16(BX[3],AX[1],acc[1][3],0,0,0); \
    acc[2][0]=__builtin_amdgcn_mfma_f32_16x16x32_bf16(BX[0],AX[2],acc[2][0],0,0,0); \
    acc[2][1]=__builtin_amdgcn_mfma_f32_16x16x32_bf16(BX[1],AX[2],acc[2][1],0,0,0); \
    acc[2][2]=__builtin_amdgcn_mfma_f32_16x16x32_bf16(BX[2],AX[2],acc[2][2],0,0,0); \
    acc[2][3]=__builtin_amdgcn_mfma_f32_16x16x32_bf16(BX[3],AX[2],acc[2][3],0,0,0); \
    acc[3][0]=__builtin_amdgcn_mfma_f32_16x16x32_bf16(BX[0],AX[3],acc[3][0],0,0,0); \
    acc[3][1]=__builtin_amdgcn_mfma_f32_16x16x32_bf16(BX[1],AX[3],acc[3][1],0,0,0); \
    acc[3][2]=__builtin_amdgcn_mfma_f32_16x16x32_bf16(BX[2],AX[3],acc[3][2],0,0,0); \
    acc[3][3]=__builtin_amdgcn_mfma_f32_16x16x32_bf16(BX[3],AX[3],acc[3][3],0,0,0);

#define RD_KS1(BC) do{ \
    A1[0] = *(const short8*)((BC) + (a0 ^ 64)); \
    A1[1] = *(const short8*)((BC) + (a1 ^ 64)); \
    A1[2] = *(const short8*)((BC) + (a2 ^ 64)); \
    A1[3] = *(const short8*)((BC) + (a3 ^ 64)); \
    B1[0] = *(const short8*)((BC) + (b0 ^ 64)); \
    B1[1] = *(const short8*)((BC) + (b1 ^ 64)); \
    B1[2] = *(const short8*)((BC) + (b2 ^ 64)); \
    B1[3] = *(const short8*)((BC) + (b3 ^ 64)); \
  }while(0)
#define RD_KS0(BN1) do{ \
    A0[0] = *(const short8*)((BN1) + a0); \
    A0[1] = *(const short8*)((BN1) + a1); \
    A0[2] = *(const short8*)((BN1) + a2); \
    A0[3] = *(const short8*)((BN1) + a3); \
    B0[0] = *(const short8*)((BN1) + b0); \
    B0[1] = *(const short8*)((BN1) + b1); \
    B0[2] = *(const short8*)((BN1) + b2); \
    B0[3] = *(const short8*)((BN1) + b3); \
  }while(0)

#define TILE(BC, BN1, STG_STMT, VM_STMT) do{ \
    RD_KS1(BC); \
    STG_STMT; \
    __builtin_amdgcn_sched_barrier(0); \
    __builtin_amdgcn_s_setprio(1); \
    MFMA16(A0, B0) \
    __builtin_amdgcn_s_setprio(0); \
    __builtin_amdgcn_sched_barrier(0); \
    VM_STMT; \
    asm volatile("s_waitcnt lgkmcnt(0)" ::: "memory"); \
    __builtin_amdgcn_sched_barrier(0); \
    __builtin_amdgcn_s_barrier(); \
    RD_KS0(BN1); \
    __builtin_amdgcn_sched_barrier(0); \
    __builtin_amdgcn_s_setprio(1); \
    MFMA16(A1, B1) \
    __builtin_amdgcn_s_setprio(0); \
    __builtin_amdgcn_sched_barrier(0); \
  }while(0)

  STG_ALL(BUF0, 0);
  STG_ALL(BUF1, 1);
  vmw<6>();
  __builtin_amdgcn_s_barrier();
  RD_KS0(BUF0);

#pragma unroll 1
  for (int i = 0; i < K3; ++i){
    const int kt = i*3;
    TILE(BUF0, BUF1, STG_ALL(BUF2, kt+2), vmw<6>());
    TILE(BUF1, BUF2, STG_ALL(BUF0, kt+3), vmw<6>());
    TILE(BUF2, BUF0, STG_ALL(BUF1, kt+4), vmw<6>());
  }
  TILE(BUF0, BUF1, STG_ALL(BUF2, NTILES-2), vmw<6>());
  TILE(BUF1, BUF2, STG_ALL(BUF0, NTILES-1), vmw<6>());
  TILE(BUF2, BUF0, (void)0, vmw<0>());
  {
    RD_KS1(BUF0);
    __builtin_amdgcn_sched_barrier(0);
    __builtin_amdgcn_s_setprio(1);
    MFMA16(A0, B0)
    __builtin_amdgcn_s_setprio(0);
    __builtin_amdgcn_sched_barrier(0);
    __builtin_amdgcn_s_setprio(1);
    MFMA16(A1, B1)
    __builtin_amdgcn_s_setprio(0);
  }
#undef TILE
#undef RD_KS0
#undef RD_KS1
#undef MFMA16
#undef STG_ALL

  const int ng4 = kg*4;
#pragma unroll
  for (int mf=0; mf<4; ++mf){
    const int m = m0 + wr*64 + mf*16 + r15;
    float wg = 0.f;
    if (G2) wg = slotw[m];
#pragma unroll
    for (int nf=0; nf<4; ++nf){
      const int nb = n0 + wn*64 + nf*16 + ng4;
      const float4 bv = *(const float4*)&bias[(size_t)e*NT + nb];
      float q0 = acc[mf][nf][0] + bv.x;
      float q1 = acc[mf][nf][1] + bv.y;
      float q2 = acc[mf][nf][2] + bv.z;
      float q3 = acc[mf][nf][3] + bv.w;
      if (!G2){
        q0=fmaxf(q0,0.f); q1=fmaxf(q1,0.f); q2=fmaxf(q2,0.f); q3=fmaxf(q3,0.f);
      } else {
        q0*=wg; q1*=wg; q2*=wg; q3*=wg;
      }
      us4 o; o[0]=f2bf(q0); o[1]=f2bf(q1); o[2]=f2bf(q2); o[3]=f2bf(q3);
      *(us4*)&Cout[(size_t)m*NT + nb] = o;
    }
  }
}

// ---------------- combine: out[t] = Y[slot0] + Y[slot1] ----------------
__global__ __launch_bounds__(256) void combine_kernel(
    const unsigned short* __restrict__ Yb, const int* __restrict__ tok_slot,
    float* __restrict__ out)
{
  const int t = blockIdx.x;
  const int tid = threadIdx.x;
  const int s0 = tok_slot[2*t], s1 = tok_slot[2*t+1];
  const us4 a = *(const us4*)&Yb[(size_t)s0*D_MODEL + tid*4];
  const us4 b = *(const us4*)&Yb[(size_t)s1*D_MODEL + tid*4];
  float4 o;
  o.x = bf2f(a[0]) + bf2f(b[0]);
  o.y = bf2f(a[1]) + bf2f(b[1]);
  o.z = bf2f(a[2]) + bf2f(b[2]);
  o.w = bf2f(a[3]) + bf2f(b[3]);
  *(float4*)&out[(size_t)t*D_MODEL + tid*4] = o;
}

extern "C" void kernel_launch(void* const* d_in, const int* in_sizes, int n_in,
                              void* d_out, int out_size, void* d_ws, size_t ws_size,
                              hipStream_t stream)
{
  const float* x  = (const float*)d_in[0];
  const float* Wr = (const float*)d_in[1];
  const float* br = (const float*)d_in[2];
  const float* W1 = (const float*)d_in[3];
  const float* b1 = (const float*)d_in[4];
  const float* W2 = (const float*)d_in[5];
  const float* b2 = (const float*)d_in[6];
  float* out = (float*)d_out;
  char* ws = (char*)d_ws;

  int*   counts  = (int*)(ws + WS_COUNTS);
  int*   cursors = (int*)(ws + WS_CURSORS);
  int*   padoff  = (int*)(ws + WS_PADOFF);
  int*   meta    = (int*)(ws + WS_META);
  int*   tileE   = (int*)(ws + WS_TILE_E);
  float* pp      = (float*)(ws + WS_PP);
  int*   top_e   = (int*)(ws + WS_TOP_E);
  float* top_w   = (float*)(ws + WS_TOP_W);
  float* slot_w  = (float*)(ws + WS_SLOT_W);
  int*   tok_slot= (int*)(ws + WS_TOK_SLOT);
  unsigned short* Xg = (unsigned short*)(ws + WS_XG);
  unsigned short* Hb = (unsigned short*)(ws + WS_HB);
  unsigned short* Wb = (unsigned short*)(ws + WS_WB);
  unsigned short* Yb = Xg;   // Xg dead after GEMM1

  hipFuncSetAttribute((const void*)moe_gemm_w<D_MODEL, EXP_D, false>,
                      hipFuncAttributeMaxDynamicSharedMemorySize, 163840);
  hipFuncSetAttribute((const void*)moe_gemm3<EXP_D, D_MODEL, true>,
                      hipFuncAttributeMaxDynamicSharedMemorySize, 147456);

  hipMemsetAsync(ws, 0, 128, stream);   // counts, cursors (padoff/meta rewritten by prefix)
  router_cvt_kernel<<<dim3(NTOK/4 + 2048), dim3(256), 0, stream>>>(
      x, Wr, br, counts, top_e, top_w, pp, W1, Wb);
  prefix_kernel<<<dim3(1), dim3(256), 0, stream>>>((int*)ws, pp, out + (size_t)NTOK*D_MODEL);
  scatter_kernel<<<dim3(NTOK/1024), dim3(1024), 0, stream>>>(top_e, top_w, cursors, padoff,
                                                             slot_w, tok_slot);
  gather_kernel<<<dim3(NTOK/4), dim3(256), 0, stream>>>(x, tok_slot, Xg);
  moe_gemm_w<D_MODEL, EXP_D, false>
      <<<dim3((EXP_D/512)*MAX_TILES), dim3(512), 163840, stream>>>(
      Xg, Wb, b1, Hb, tileE, meta, slot_w);
  cvt_kernel<<<dim3(2048), dim3(256), 0, stream>>>(W2, Wb);
  moe_gemm3<EXP_D, D_MODEL, true>
      <<<dim3((D_MODEL/256)*MAX_TILES), dim3(512), 147456, stream>>>(
      Hb, Wb, b2, Yb, tileE, meta, slot_w);
  combine_kernel<<<dim3(NTOK), dim3(256), 0, stream>>>(Yb, tok_slot, out);
}

// Round 9
// 508.511 us; speedup vs baseline: 1.7510x; 1.3336x over previous
//
#include <hip/hip_runtime.h>
#include <stdint.h>

#define D_MODEL 1024
#define EXP_D   4096
#define NE      8
#define NTOK    8192
#define BMT     128
#define MAX_TILES 136
#define NS_MAX  17408   // MAX_TILES*128

typedef __attribute__((ext_vector_type(8))) short short8;
typedef __attribute__((ext_vector_type(4))) float f32x4;
typedef __attribute__((ext_vector_type(4))) unsigned short us4;

// ---- workspace layout (bytes) ----
#define WS_COUNTS    0          // int[8] (unused now)
#define WS_CURSORS   32         // int[8]  <- scatter accumulates counts here
#define WS_PADOFF    64         // int[16]
#define WS_META      128        // int[32], meta[0]=ntiles
#define WS_TILE_E    256        // int[256]
#define WS_PP        4096       // float[2048*8]
#define WS_TOP_E     69632      // int[16384]
#define WS_TOP_W     135168     // float[16384]
#define WS_TOK_RANK  200704     // int[16384]
#define WS_SLOT_W    270336     // float[17408]
#define WS_TOK_SLOT  339968     // int[16384]
#define WS_XG        405504     // bf16 [17408][1024]  (Yb aliases this)
#define WS_HB        36057088   // bf16 [17408][4096]
#define WS_WB        178663424  // bf16 [8][4096][1024] -> ends 245,772,288

__device__ __forceinline__ unsigned short f2bf(float f){
  __bf16 h = (__bf16)f;
  return __builtin_bit_cast(unsigned short, h);
}
__device__ __forceinline__ float bf2f(unsigned short u){
  unsigned int v = ((unsigned int)u) << 16;
  return __builtin_bit_cast(float, v);
}
__device__ __forceinline__ void gl_lds16(const void* g, void* l){
  __builtin_amdgcn_global_load_lds((const __attribute__((address_space(1))) unsigned int*)g,
                                   (__attribute__((address_space(3))) unsigned int*)l,
                                   16, 0, 0);
}

template<int N> __device__ __forceinline__ void vmw(){
  if constexpr (N==0)      asm volatile("s_waitcnt vmcnt(0)" ::: "memory");
  else if constexpr (N==6) asm volatile("s_waitcnt vmcnt(6)" ::: "memory");
}

// ---------------- router (blocks 0..2047, NO atomics) + W1 cvt (blocks 2048..4095) ----------------
__global__ __launch_bounds__(256) void router_cvt_kernel(
    const float* __restrict__ x, const float* __restrict__ Wr,
    const float* __restrict__ br,
    int* __restrict__ top_e, float* __restrict__ top_w,
    float* __restrict__ pp,
    const float* __restrict__ W1, unsigned short* __restrict__ Wb)
{
  const int tid = threadIdx.x;
  if ((int)blockIdx.x >= NTOK/4){
    const int n4 = NE*EXP_D*D_MODEL/4;
    for (int i = ((int)blockIdx.x - NTOK/4)*256 + tid; i < n4; i += 2048*256){
      const float4 v = *(const float4*)&W1[(size_t)i*4];
      us4 o; o[0]=f2bf(v.x); o[1]=f2bf(v.y); o[2]=f2bf(v.z); o[3]=f2bf(v.w);
      *(us4*)&Wb[(size_t)i*4] = o;
    }
    return;
  }
  __shared__ float WrS[NE*D_MODEL];
  __shared__ float wprob[4][NE];
#pragma unroll
  for (int i=0;i<8;++i){
    int j = (tid + i*256)*4;
    *(float4*)&WrS[j] = *(const float4*)&Wr[j];
  }
  __syncthreads();
  const int w = tid>>6, lane = tid&63;
  const int t = blockIdx.x*4 + w;
  const float* xt = x + (size_t)t*D_MODEL;
  float accv[8] = {0,0,0,0,0,0,0,0};
#pragma unroll
  for (int i=0;i<4;++i){
    const int k = i*256 + lane*4;
    const float4 xv = *(const float4*)&xt[k];
#pragma unroll
    for (int e=0;e<8;++e){
      const float4 wv = *(const float4*)&WrS[e*D_MODEL + k];
      accv[e] += xv.x*wv.x + xv.y*wv.y + xv.z*wv.z + xv.w*wv.w;
    }
  }
#pragma unroll
  for (int m=32;m>0;m>>=1){
#pragma unroll
    for (int e=0;e<8;++e) accv[e] += __shfl_xor(accv[e], m, 64);
  }
  if (lane==0){
    float lg[8];
#pragma unroll
    for (int e=0;e<8;++e) lg[e] = accv[e] + br[e];
    float mx = lg[0];
#pragma unroll
    for (int e=1;e<8;++e) mx = fmaxf(mx, lg[e]);
    float p[8]; float s=0.f;
#pragma unroll
    for (int e=0;e<8;++e){ p[e] = __expf(lg[e]-mx); s += p[e]; }
    const float inv = 1.f/s;
#pragma unroll
    for (int e=0;e<8;++e){ p[e] *= inv; wprob[w][e] = p[e]; }
    int i1=0; float p1v=p[0];
#pragma unroll
    for (int e=1;e<8;++e) if (p[e] > p1v){ p1v=p[e]; i1=e; }
    int i2=-1; float p2v=-1.f;
#pragma unroll
    for (int e=0;e<8;++e) if (e!=i1 && p[e] > p2v){ p2v=p[e]; i2=e; }
    const float rn = 1.f/(p1v+p2v);
    top_e[2*t]   = i1; top_w[2*t]   = p1v*rn;
    top_e[2*t+1] = i2; top_w[2*t+1] = p2v*rn;
  }
  __syncthreads();
  if (tid<8){
    pp[blockIdx.x*8+tid] = wprob[0][tid]+wprob[1][tid]+wprob[2][tid]+wprob[3][tid];
  }
}

// ---------------- weight fp32 -> bf16 convert (standalone, for W2) ----------------
__global__ __launch_bounds__(256) void cvt_kernel(const float* __restrict__ W,
                                                  unsigned short* __restrict__ Wb){
  const int n4 = NE*EXP_D*D_MODEL/4;
  for (int i = blockIdx.x*256 + threadIdx.x; i < n4; i += gridDim.x*256){
    const float4 v = *(const float4*)&W[(size_t)i*4];
    us4 o; o[0]=f2bf(v.x); o[1]=f2bf(v.y); o[2]=f2bf(v.z); o[3]=f2bf(v.w);
    *(us4*)&Wb[(size_t)i*4] = o;
  }
}

// ---------------- scatter: LDS-aggregated counting + expert-local ranks ----------------
// 8 blocks x 1024 thr; 64 global atomics total. cursors ends up = per-expert counts.
__global__ __launch_bounds__(1024) void scatter_kernel(
    const int* __restrict__ top_e,
    int* __restrict__ cursors, int* __restrict__ tok_rank)
{
  __shared__ int cnt[NE];
  __shared__ int base[NE];
  const int tid = threadIdx.x;
  if (tid < NE) cnt[tid] = 0;
  __syncthreads();
  const int t = blockIdx.x*1024 + tid;
  const int e0 = top_e[2*t], e1 = top_e[2*t+1];
  const int p0 = atomicAdd(&cnt[e0], 1);
  const int p1 = atomicAdd(&cnt[e1], 1);
  __syncthreads();
  if (tid < NE) base[tid] = atomicAdd(&cursors[tid], cnt[tid]);
  __syncthreads();
  tok_rank[2*t]   = base[e0] + p0;
  tok_rank[2*t+1] = base[e1] + p1;
}

// ---------------- prefix (AFTER scatter): tile table + aux loss ----------------
__global__ __launch_bounds__(256) void prefix_kernel(int* __restrict__ wsI,
                                                     const float* __restrict__ pp,
                                                     float* __restrict__ aux_out){
  const int tid = threadIdx.x;
  int* counts = wsI + 8;    // cursors (= final per-expert counts after scatter)
  int* padoff = wsI + 16;
  int* meta   = wsI + 32;
  int* tileE  = wsI + 64;
  __shared__ int tileCum[9];
  __shared__ float dev2[8];
  if (tid==0){
    int nt = 0;
    tileCum[0] = 0;
    for (int e=0;e<NE;++e){
      padoff[e] = nt*BMT;
      nt += (counts[e] + BMT - 1) >> 7;
      tileCum[e+1] = nt;
    }
    meta[0] = nt;
  }
  __syncthreads();
  const int nt = tileCum[8];
  for (int i=tid; i<nt; i+=256){
    int e = 0;
    while (tileCum[e+1] <= i) ++e;
    tileE[i] = e;
  }
  const int ex = tid>>5, j = tid&31;
  float s = 0.f;
  for (int b=j; b<NTOK/4; b+=32) s += pp[b*8+ex];
#pragma unroll
  for (int m=16;m>0;m>>=1) s += __shfl_xor(s, m, 64);
  if (j==0){ float d = s*(1.f/(float)NTOK) - 0.125f; dev2[ex] = d*d; }
  __syncthreads();
  if (tid==0){
    float a=0.f;
#pragma unroll
    for (int e=0;e<8;++e) a += dev2[e];
    aux_out[0] = a;
  }
}

// ---------------- gather: slot = padoff[e] + rank; write tok_slot/slot_w/Xg rows ----------------
__global__ __launch_bounds__(256) void gather_kernel(
    const float* __restrict__ x, const int* __restrict__ top_e,
    const float* __restrict__ top_w, const int* __restrict__ tok_rank,
    const int* __restrict__ padoff,
    int* __restrict__ tok_slot, float* __restrict__ slot_w,
    unsigned short* __restrict__ Xg)
{
  const int w = threadIdx.x>>6, lane = threadIdx.x&63;
  const int t = blockIdx.x*4 + w;
  const int s0 = padoff[top_e[2*t]]   + tok_rank[2*t];
  const int s1 = padoff[top_e[2*t+1]] + tok_rank[2*t+1];
  if (lane==0){
    tok_slot[2*t] = s0; tok_slot[2*t+1] = s1;
    slot_w[s0] = top_w[2*t]; slot_w[s1] = top_w[2*t+1];
  }
  us4 o[4];
#pragma unroll
  for (int i=0;i<4;++i){
    const float4 v = *(const float4*)&x[(size_t)t*D_MODEL + i*256 + lane*4];
    o[i][0]=f2bf(v.x); o[i][1]=f2bf(v.y); o[i][2]=f2bf(v.z); o[i][3]=f2bf(v.w);
  }
#pragma unroll
  for (int i=0;i<4;++i) *(us4*)&Xg[(size_t)s0*D_MODEL + i*256 + lane*4] = o[i];
#pragma unroll
  for (int i=0;i<4;++i) *(us4*)&Xg[(size_t)s1*D_MODEL + i*256 + lane*4] = o[i];
}

// ============ GEMM1: 128x512 tile, BK=64, 8 waves (wave tile 128x64), 2-buf 160KB ============
template<int KT, int NT, bool G2>
__global__ __launch_bounds__(512,1) void moe_gemm_w(
    const unsigned short* __restrict__ A,
    const unsigned short* __restrict__ Wb,
    const float* __restrict__ bias,
    unsigned short* __restrict__ Cout,
    const int* __restrict__ tileE,
    const int* __restrict__ meta,
    const float* __restrict__ slotw)
{
  constexpr int NX = NT/512;
  constexpr int TOTAL = NX*MAX_TILES;
  constexpr int Q = TOTAL/8, R = TOTAL%8;
  constexpr int NTILES = KT/64;
  static_assert(NTILES%2==0, "even K-tiles");

  const int lid = blockIdx.x;
  const int xcc = lid & 7, jj = lid >> 3;
  const int tsw = xcc*Q + (xcc < R ? xcc : R) + jj;
  const int mtile = tsw / NX, ntile = tsw - mtile*NX;
  if (mtile >= meta[0]) return;

  extern __shared__ char smem[];
  char* const BUF0 = smem;
  char* const BUF1 = smem + 81920;

  const int tid = threadIdx.x;
  const int w = tid>>6, lane = tid&63;
  const int r15 = lane&15, kg = lane>>4;
  const int e  = tileE[mtile];
  const int m0 = mtile*BMT;
  const int n0 = ntile*512;

  const int trow = tid>>3;
  const int tch  = ((tid&7) ^ (trow&7))*8;
  const unsigned short* sA = A  + (size_t)(m0 + trow)*KT + tch;
  const unsigned short* sB = Wb + (size_t)e*NT*KT + (size_t)(n0 + trow)*KT + tch;

#define WSTG(BS, KTT) do{ \
    gl_lds16(sA + (size_t)(KTT)*64,                  (BS) + tid*16); \
    gl_lds16(sA + (size_t)(KTT)*64 + (size_t)64*KT,  (BS) + 8192 + tid*16); \
    _Pragma("unroll") \
    for (int jq=0;jq<8;++jq) \
      gl_lds16(sB + (size_t)(KTT)*64 + (size_t)(64*jq)*KT, (BS) + 16384 + jq*8192 + tid*16); \
  }while(0)

  const int key4  = (kg ^ (r15&7))<<4;
  const int abase = r15*128 + key4;
  const int bbase = 16384 + w*8192 + r15*128 + key4;

  f32x4 acc[8][4];
#pragma unroll
  for (int i=0;i<8;++i)
#pragma unroll
    for (int j=0;j<4;++j) acc[i][j] = (f32x4){0.f,0.f,0.f,0.f};

  short8 A0[8], A1[8], B0[4], B1[4];

#define RD0(BB) do{ const char* pa=(BB)+abase; const char* pb=(BB)+bbase; \
  _Pragma("unroll") for(int q=0;q<8;++q) A0[q]=*(const short8*)(pa+q*2048); \
  _Pragma("unroll") for(int q=0;q<4;++q) B0[q]=*(const short8*)(pb+q*2048); }while(0)
#define RD1(BB) do{ const char* pa=(BB)+(abase^64); const char* pb=(BB)+(bbase^64); \
  _Pragma("unroll") for(int q=0;q<8;++q) A1[q]=*(const short8*)(pa+q*2048); \
  _Pragma("unroll") for(int q=0;q<4;++q) B1[q]=*(const short8*)(pb+q*2048); }while(0)

#define MM32(AX,BX) do{ \
  _Pragma("unroll") for(int mi=0;mi<8;++mi) \
  _Pragma("unroll") for(int nf=0;nf<4;++nf) \
    acc[mi][nf]=__builtin_amdgcn_mfma_f32_16x16x32_bf16(BX[nf],AX[mi],acc[mi][nf],0,0,0); \
}while(0)

#define WTILE(BC,BN1,STG_STMT) do{ \
  RD1(BC); \
  STG_STMT; \
  __builtin_amdgcn_sched_barrier(0); \
  __builtin_amdgcn_s_setprio(1); MM32(A0,B0); __builtin_amdgcn_s_setprio(0); \
  __builtin_amdgcn_sched_barrier(0); \
  asm volatile("s_waitcnt vmcnt(0)" ::: "memory"); \
  asm volatile("s_waitcnt lgkmcnt(0)" ::: "memory"); \
  __builtin_amdgcn_sched_barrier(0); \
  __builtin_amdgcn_s_barrier(); \
  RD0(BN1); \
  __builtin_amdgcn_sched_barrier(0); \
  __builtin_amdgcn_s_setprio(1); MM32(A1,B1); __builtin_amdgcn_s_setprio(0); \
  __builtin_amdgcn_sched_barrier(0); \
}while(0)

  WSTG(BUF0, 0);
  asm volatile("s_waitcnt vmcnt(0)" ::: "memory");
  __builtin_amdgcn_s_barrier();
  RD0(BUF0);

#pragma unroll 1
  for (int i = 0; i < (NTILES-2)/2; ++i){
    WTILE(BUF0, BUF1, WSTG(BUF1, 2*i+1));
    WTILE(BUF1, BUF0, WSTG(BUF0, 2*i+2));
  }
  WTILE(BUF0, BUF1, WSTG(BUF1, NTILES-1));
  {
    RD1(BUF1);
    __builtin_amdgcn_sched_barrier(0);
    __builtin_amdgcn_s_setprio(1); MM32(A0,B0); __builtin_amdgcn_s_setprio(0);
    asm volatile("s_waitcnt lgkmcnt(0)" ::: "memory");
    __builtin_amdgcn_sched_barrier(0);
    __builtin_amdgcn_s_setprio(1); MM32(A1,B1); __builtin_amdgcn_s_setprio(0);
  }
#undef WTILE
#undef MM32
#undef RD0
#undef RD1
#undef WSTG

  const int ng4 = kg*4;
#pragma unroll
  for (int mi=0; mi<8; ++mi){
    const int m = m0 + mi*16 + r15;
    float wg = 0.f;
    if (G2) wg = slotw[m];
#pragma unroll
    for (int nf=0; nf<4; ++nf){
      const int nb = n0 + w*64 + nf*16 + ng4;
      const float4 bv = *(const float4*)&bias[(size_t)e*NT + nb];
      float q0 = acc[mi][nf][0] + bv.x;
      float q1 = acc[mi][nf][1] + bv.y;
      float q2 = acc[mi][nf][2] + bv.z;
      float q3 = acc[mi][nf][3] + bv.w;
      if (!G2){
        q0=fmaxf(q0,0.f); q1=fmaxf(q1,0.f); q2=fmaxf(q2,0.f); q3=fmaxf(q3,0.f);
      } else {
        q0*=wg; q1*=wg; q2*=wg; q3*=wg;
      }
      us4 o; o[0]=f2bf(q0); o[1]=f2bf(q1); o[2]=f2bf(q2); o[3]=f2bf(q3);
      *(us4*)&Cout[(size_t)m*NT + nb] = o;
    }
  }
}

// ============ GEMM2: 128x256, BK=64, 8 waves, 3-buf pipeline ============
template<int KT, int NT, bool G2>
__global__ __launch_bounds__(512,1) void moe_gemm3(
    const unsigned short* __restrict__ A,
    const unsigned short* __restrict__ Wb,
    const float* __restrict__ bias,
    unsigned short* __restrict__ Cout,
    const int* __restrict__ tileE,
    const int* __restrict__ meta,
    const float* __restrict__ slotw)
{
  constexpr int NX = NT/256;
  constexpr int TOTAL = NX*MAX_TILES;
  constexpr int Q = TOTAL/8, R = TOTAL%8;
  constexpr int NTILES = KT/64;
  constexpr int K3 = (NTILES-4)/3;
  static_assert((NTILES-4)%3 == 0, "tail peel needs (NTILES-4)%3==0");

  const int lid = blockIdx.x;
  const int xcc = lid & 7, jj = lid >> 3;
  const int tsw = xcc*Q + (xcc < R ? xcc : R) + jj;
  const int mtile = tsw / NX, ntile = tsw - mtile*NX;
  if (mtile >= meta[0]) return;

  extern __shared__ char smem[];
  char* const BUF0 = smem;
  char* const BUF1 = smem + 49152;
  char* const BUF2 = smem + 98304;

  const int tid = threadIdx.x;
  const int w = tid>>6, lane = tid&63;
  const int wr = w>>2, wn = w&3;
  const int r15 = lane&15, kg = lane>>4;
  const int e  = tileE[mtile];
  const int m0 = mtile*BMT;
  const int n0 = ntile*256;

  const int trow = tid>>3;
  const int tch  = ((tid&7) ^ (trow&7))*8;
  const unsigned short* sA = A  + (size_t)(m0 + trow)*KT + tch;
  const unsigned short* sB = Wb + (size_t)e*NT*KT + (size_t)(n0 + trow)*KT + tch;

#define STG_ALL(BS, KTT) do{ \
    gl_lds16(sA + (size_t)(KTT)*64,                  (BS) + tid*16); \
    gl_lds16(sA + (size_t)(KTT)*64 + (size_t)64*KT,  (BS) + 8192  + tid*16); \
    gl_lds16(sB + (size_t)(KTT)*64,                  (BS) + 16384 + tid*16); \
    gl_lds16(sB + (size_t)(KTT)*64 + (size_t)64*KT,  (BS) + 24576 + tid*16); \
    gl_lds16(sB + (size_t)(KTT)*64 + (size_t)128*KT, (BS) + 32768 + tid*16); \
    gl_lds16(sB + (size_t)(KTT)*64 + (size_t)192*KT, (BS) + 40960 + tid*16); \
  }while(0)

  const int key4 = (kg ^ (r15&7))<<4;
  const int a0 = (wr*64 + 0*16 + r15)*128 + key4;
  const int a1 = (wr*64 + 1*16 + r15)*128 + key4;
  const int a2 = (wr*64 + 2*16 + r15)*128 + key4;
  const int a3 = (wr*64 + 3*16 + r15)*128 + key4;
  const int b0 = 16384 + (wn*64 + 0*16 + r15)*128 + key4;
  const int b1 = 16384 + (wn*64 + 1*16 + r15)*128 + key4;
  const int b2 = 16384 + (wn*64 + 2*16 + r15)*128 + key4;
  const int b3 = 16384 + (wn*64 + 3*16 + r15)*128 + key4;

  f32x4 acc[4][4];
#pragma unroll
  for (int i=0;i<4;++i)
#pragma unroll
    for (int j=0;j<4;++j) acc[i][j] = (f32x4){0.f,0.f,0.f,0.f};

  short8 A0[4], B0[4], A1[4], B1[4];

#define MFMA16(AX, BX) \
    acc[0][0]=__builtin_amdgcn_mfma_f32_16x16x32_bf16(BX[0],AX[0],acc[0][0],0,0,0); \
    acc[0][1]=__builtin_amdgcn_mfma_f32_16x16x32_bf16(BX[1],AX[0],acc[0][1],0,0,0); \
    acc[0][2]=__builtin_amdgcn_mfma_f32_16x16x32_bf16(BX[2],AX[0],acc[0][2],0,0,0); \
    acc[0][3]=__builtin_amdgcn_mfma_f32_16x16x32_bf16(BX[3],AX[0],acc[0][3],0,0,0); \
    acc[1][0]=__builtin_amdgcn_mfma_f32_16x16x32_bf16(BX[0],AX[1],acc[1][0],0,0,0); \
    acc[1][1]=__builtin_amdgcn_mfma_f32_16x16x32_bf16(BX[1],AX[1],acc[1][1],0,0,0); \
    acc[1][2]=__builtin_amdgcn_mfma_f32_16x16x32_bf16(BX[2],AX[1],acc[1][2],0,0,0); \
    acc[1][3]=__builtin_amdgcn_mfma_f32_16x16x32_bf16(BX[3],AX[1],acc[1][3],0,0,0); \
    acc[2][0]=__builtin_amdgcn_mfma_f32_16x16x32_bf16(BX[0],AX[2],acc[2][0],0,0,0); \
    acc[2][1]=__builtin_amdgcn_mfma_f32_16x16x32_bf16(BX[1],AX[2],acc[2][1],0,0,0); \
    acc[2][2]=__builtin_amdgcn_mfma_f32_16x16x32_bf16(BX[2],AX[2],acc[2][2],0,0,0); \
    acc[2][3]=__builtin_amdgcn_mfma_f32_16x16x32_bf16(BX[3],AX[2],acc[2][3],0,0,0); \
    acc[3][0]=__builtin_amdgcn_mfma_f32_16x16x32_bf16(BX[0],AX[3],acc[3][0],0,0,0); \
    acc[3][1]=__builtin_amdgcn_mfma_f32_16x16x32_bf16(BX[1],AX[3],acc[3][1],0,0,0); \
    acc[3][2]=__builtin_amdgcn_mfma_f32_16x16x32_bf16(BX[2],AX[3],acc[3][2],0,0,0); \
    acc[3][3]=__builtin_amdgcn_mfma_f32_16x16x32_bf16(BX[3],AX[3],acc[3][3],0,0,0);

#define RD_KS1(BC) do{ \
    A1[0] = *(const short8*)((BC) + (a0 ^ 64)); \
    A1[1] = *(const short8*)((BC) + (a1 ^ 64)); \
    A1[2] = *(const short8*)((BC) + (a2 ^ 64)); \
    A1[3] = *(const short8*)((BC) + (a3 ^ 64)); \
    B1[0] = *(const short8*)((BC) + (b0 ^ 64)); \
    B1[1] = *(const short8*)((BC) + (b1 ^ 64)); \
    B1[2] = *(const short8*)((BC) + (b2 ^ 64)); \
    B1[3] = *(const short8*)((BC) + (b3 ^ 64)); \
  }while(0)
#define RD_KS0(BN1) do{ \
    A0[0] = *(const short8*)((BN1) + a0); \
    A0[1] = *(const short8*)((BN1) + a1); \
    A0[2] = *(const short8*)((BN1) + a2); \
    A0[3] = *(const short8*)((BN1) + a3); \
    B0[0] = *(const short8*)((BN1) + b0); \
    B0[1] = *(const short8*)((BN1) + b1); \
    B0[2] = *(const short8*)((BN1) + b2); \
    B0[3] = *(const short8*)((BN1) + b3); \
  }while(0)

#define TILE(BC, BN1, STG_STMT, VM_STMT) do{ \
    RD_KS1(BC); \
    STG_STMT; \
    __builtin_amdgcn_sched_barrier(0); \
    __builtin_amdgcn_s_setprio(1); \
    MFMA16(A0, B0) \
    __builtin_amdgcn_s_setprio(0); \
    __builtin_amdgcn_sched_barrier(0); \
    VM_STMT; \
    asm volatile("s_waitcnt lgkmcnt(0)" ::: "memory"); \
    __builtin_amdgcn_sched_barrier(0); \
    __builtin_amdgcn_s_barrier(); \
    RD_KS0(BN1); \
    __builtin_amdgcn_sched_barrier(0); \
    __builtin_amdgcn_s_setprio(1); \
    MFMA16(A1, B1) \
    __builtin_amdgcn_s_setprio(0); \
    __builtin_amdgcn_sched_barrier(0); \
  }while(0)

  STG_ALL(BUF0, 0);
  STG_ALL(BUF1, 1);
  vmw<6>();
  __builtin_amdgcn_s_barrier();
  RD_KS0(BUF0);

#pragma unroll 1
  for (int i = 0; i < K3; ++i){
    const int kt = i*3;
    TILE(BUF0, BUF1, STG_ALL(BUF2, kt+2), vmw<6>());
    TILE(BUF1, BUF2, STG_ALL(BUF0, kt+3), vmw<6>());
    TILE(BUF2, BUF0, STG_ALL(BUF1, kt+4), vmw<6>());
  }
  TILE(BUF0, BUF1, STG_ALL(BUF2, NTILES-2), vmw<6>());
  TILE(BUF1, BUF2, STG_ALL(BUF0, NTILES-1), vmw<6>());
  TILE(BUF2, BUF0, (void)0, vmw<0>());
  {
    RD_KS1(BUF0);
    __builtin_amdgcn_sched_barrier(0);
    __builtin_amdgcn_s_setprio(1);
    MFMA16(A0, B0)
    __builtin_amdgcn_s_setprio(0);
    __builtin_amdgcn_sched_barrier(0);
    __builtin_amdgcn_s_setprio(1);
    MFMA16(A1, B1)
    __builtin_amdgcn_s_setprio(0);
  }
#undef TILE
#undef RD_KS0
#undef RD_KS1
#undef MFMA16
#undef STG_ALL

  const int ng4 = kg*4;
#pragma unroll
  for (int mf=0; mf<4; ++mf){
    const int m = m0 + wr*64 + mf*16 + r15;
    float wg = 0.f;
    if (G2) wg = slotw[m];
#pragma unroll
    for (int nf=0; nf<4; ++nf){
      const int nb = n0 + wn*64 + nf*16 + ng4;
      const float4 bv = *(const float4*)&bias[(size_t)e*NT + nb];
      float q0 = acc[mf][nf][0] + bv.x;
      float q1 = acc[mf][nf][1] + bv.y;
      float q2 = acc[mf][nf][2] + bv.z;
      float q3 = acc[mf][nf][3] + bv.w;
      if (!G2){
        q0=fmaxf(q0,0.f); q1=fmaxf(q1,0.f); q2=fmaxf(q2,0.f); q3=fmaxf(q3,0.f);
      } else {
        q0*=wg; q1*=wg; q2*=wg; q3*=wg;
      }
      us4 o; o[0]=f2bf(q0); o[1]=f2bf(q1); o[2]=f2bf(q2); o[3]=f2bf(q3);
      *(us4*)&Cout[(size_t)m*NT + nb] = o;
    }
  }
}

// ---------------- combine: out[t] = Y[slot0] + Y[slot1] ----------------
__global__ __launch_bounds__(256) void combine_kernel(
    const unsigned short* __restrict__ Yb, const int* __restrict__ tok_slot,
    float* __restrict__ out)
{
  const int t = blockIdx.x;
  const int tid = threadIdx.x;
  const int s0 = tok_slot[2*t], s1 = tok_slot[2*t+1];
  const us4 a = *(const us4*)&Yb[(size_t)s0*D_MODEL + tid*4];
  const us4 b = *(const us4*)&Yb[(size_t)s1*D_MODEL + tid*4];
  float4 o;
  o.x = bf2f(a[0]) + bf2f(b[0]);
  o.y = bf2f(a[1]) + bf2f(b[1]);
  o.z = bf2f(a[2]) + bf2f(b[2]);
  o.w = bf2f(a[3]) + bf2f(b[3]);
  *(float4*)&out[(size_t)t*D_MODEL + tid*4] = o;
}

extern "C" void kernel_launch(void* const* d_in, const int* in_sizes, int n_in,
                              void* d_out, int out_size, void* d_ws, size_t ws_size,
                              hipStream_t stream)
{
  const float* x  = (const float*)d_in[0];
  const float* Wr = (const float*)d_in[1];
  const float* br = (const float*)d_in[2];
  const float* W1 = (const float*)d_in[3];
  const float* b1 = (const float*)d_in[4];
  const float* W2 = (const float*)d_in[5];
  const float* b2 = (const float*)d_in[6];
  float* out = (float*)d_out;
  char* ws = (char*)d_ws;

  int*   cursors = (int*)(ws + WS_CURSORS);
  int*   padoff  = (int*)(ws + WS_PADOFF);
  int*   meta    = (int*)(ws + WS_META);
  int*   tileE   = (int*)(ws + WS_TILE_E);
  float* pp      = (float*)(ws + WS_PP);
  int*   top_e   = (int*)(ws + WS_TOP_E);
  float* top_w   = (float*)(ws + WS_TOP_W);
  int*   tok_rank= (int*)(ws + WS_TOK_RANK);
  float* slot_w  = (float*)(ws + WS_SLOT_W);
  int*   tok_slot= (int*)(ws + WS_TOK_SLOT);
  unsigned short* Xg = (unsigned short*)(ws + WS_XG);
  unsigned short* Hb = (unsigned short*)(ws + WS_HB);
  unsigned short* Wb = (unsigned short*)(ws + WS_WB);
  unsigned short* Yb = Xg;   // Xg dead after GEMM1

  hipFuncSetAttribute((const void*)moe_gemm_w<D_MODEL, EXP_D, false>,
                      hipFuncAttributeMaxDynamicSharedMemorySize, 163840);
  hipFuncSetAttribute((const void*)moe_gemm3<EXP_D, D_MODEL, true>,
                      hipFuncAttributeMaxDynamicSharedMemorySize, 147456);

  hipMemsetAsync(ws, 0, 128, stream);   // counts/cursors zero
  router_cvt_kernel<<<dim3(NTOK/4 + 2048), dim3(256), 0, stream>>>(
      x, Wr, br, top_e, top_w, pp, W1, Wb);
  scatter_kernel<<<dim3(NTOK/1024), dim3(1024), 0, stream>>>(top_e, cursors, tok_rank);
  prefix_kernel<<<dim3(1), dim3(256), 0, stream>>>((int*)ws, pp, out + (size_t)NTOK*D_MODEL);
  gather_kernel<<<dim3(NTOK/4), dim3(256), 0, stream>>>(x, top_e, top_w, tok_rank, padoff,
                                                        tok_slot, slot_w, Xg);
  moe_gemm_w<D_MODEL, EXP_D, false>
      <<<dim3((EXP_D/512)*MAX_TILES), dim3(512), 163840, stream>>>(
      Xg, Wb, b1, Hb, tileE, meta, slot_w);
  cvt_kernel<<<dim3(2048), dim3(256), 0, stream>>>(W2, Wb);
  moe_gemm3<EXP_D, D_MODEL, true>
      <<<dim3((D_MODEL/256)*MAX_TILES), dim3(512), 147456, stream>>>(
      Hb, Wb, b2, Yb, tileE, meta, slot_w);
  combine_kernel<<<dim3(NTOK), dim3(256), 0, stream>>>(Yb, tok_slot, out);
}